// Round 20
// baseline (565.471 us; speedup 1.0000x reference)
//
#include <hip/hip_runtime.h>

#define DIMS 3
#define NB 256
#define NN 256
#define KK 16
#define HID 64
#define EPG 8192
#define NTOT (NB*NN)
#define NE (NB*EPG)

// d_out layout (flat concat of reference outputs, all as float)
#define PX_OFF   0          // (B*K, F, DIMS)           = 786432
#define PEI_OFF  786432     // (2, B*K*K)               = 131072
#define PEA_OFF  917504     // (B*K*K, DIMS)            = 196608
#define PB_OFF   1114112    // (B*K,)                   = 4096
#define LOSS_OFF 1118208    // scalar
#define S_OFF    1118209    // (DIMS, B, N, K)          = 3145728

// d_ws layout (bytes) — total ~27.5 MB
#define WREC_WS  0                 // float[3][NB*EPG] per-d edge weight (CSR order) = 24 MB
#define CLREC_WS 25165824          // uchar[NB*EPG] col-local index
#define IPTR_WS  27262976          // int[NB*257]
#define ENT_WS   27526144          // float[768]
#define MOD_WS   27529216          // float[768]
#define WC_WS    27532288          // float[144*16]  (fcW1 @ fcW2)
#define BC_WS    27541504          // float[16]      (fcb1 @ fcW2 + fcb2)

// LDS float-offsets inside hb (16384 floats) for the fused pool epilogue
#define SL_OFF   0         // s tile      [256][20]  -> [0, 5120)
#define GL_OFF   5120      // G tile      [256][20]  -> [5120, 10240)
#define PXP_OFF  10240     // px partials [16][64][4]-> [10240, 14336)
#define PJW_OFF  14336     // padj part.  [4][256]   -> [14336, 15360)
#define MRED_OFF 15360     // mod red     [16]
#define ERED_OFF 15380     // ent red     [16]

// Layout map: logical (row, chunk c in 0..15) stored at
//   phys(c,row) = (c&8) | ((c&7) ^ ((row>>1)&7))
// -> both rows of a pair share the swizzle key; chunk c+8 is at constant +128B.

// ---------------- combined FC weights: Wc = fcW1@fcW2, bc = fcb1@fcW2+fcb2 ----------------
__global__ void fc_combine(const float* __restrict__ fcW1, const float* __restrict__ fcb1,
                           const float* __restrict__ fcW2, const float* __restrict__ fcb2,
                           float* __restrict__ wc, float* __restrict__ bc)
{
    const int t = threadIdx.x;
    for (int idx = t; idx < 144 * 16; idx += 256) {
        const int i = idx >> 4, k = idx & 15;
        float s = 0.f;
        for (int q = 0; q < 50; ++q) s += fcW1[i * 50 + q] * fcW2[q * 16 + k];
        wc[idx] = s;
    }
    if (t < 16) {
        float s = fcb2[t];
        for (int q = 0; q < 50; ++q) s += fcb1[q] * fcW2[q * 16 + t];
        bc[t] = s;
    }
}

// ------- CSR build: parallel deterministic counting sort (strided chunks) -------
#define HSTR 132
#define PSTR 129
__launch_bounds__(256)
__global__ void csr_build(const int* __restrict__ edge_index,
                          const float* __restrict__ edge_attr,
                          float* __restrict__ wrec, unsigned char* __restrict__ clrec,
                          int* __restrict__ indptr)
{
    __shared__ unsigned char  h[256 * HSTR];    // 33.8 KB
    __shared__ unsigned short po[256 * PSTR];   // 66.0 KB
    __shared__ int sc[256];
    const int b = blockIdx.x;
    const int t = threadIdx.x;
    const int* rowp = edge_index + (size_t)b * EPG;
    const int* colp = edge_index + (size_t)NB * EPG + (size_t)b * EPG;

    for (int i = t; i < 256 * HSTR / 4; i += 256) ((unsigned int*)h)[i] = 0u;
    __syncthreads();

    if (t < 128) {
        #pragma unroll 4
        for (int j = 0; j < 64; ++j) {
            const int r = rowp[t + 128 * j] & (NN - 1);
            h[r * HSTR + t]++;
        }
    }
    __syncthreads();

    int tot;
    {
        int s = 0;
        const unsigned int* hr = (const unsigned int*)(h + t * HSTR);
        #pragma unroll
        for (int c4 = 0; c4 < HSTR / 4; ++c4) {
            const unsigned int v = hr[c4];
            s += (v & 255) + ((v >> 8) & 255) + ((v >> 16) & 255) + (v >> 24);
        }
        tot = s;
        sc[t] = s;
    }
    __syncthreads();
    for (int ofs = 1; ofs < 256; ofs <<= 1) {
        int v = (t >= ofs) ? sc[t - ofs] : 0;
        __syncthreads();
        sc[t] += v;
        __syncthreads();
    }
    const int start = sc[t] - tot;
    indptr[b * 257 + t] = start;
    if (t == 255) indptr[b * 257 + 256] = EPG;

    {
        int run = start;
        #pragma unroll 4
        for (int c = 0; c < 128; ++c) {
            po[t * PSTR + c] = (unsigned short)run;
            run += h[t * HSTR + c];
        }
    }
    __syncthreads();

    if (t < 128) {
        const float* eap = edge_attr + (size_t)b * EPG * 3;
        float* w0 = wrec + (size_t)b * EPG;
        float* w1 = wrec + (size_t)NB * EPG + (size_t)b * EPG;
        float* w2 = wrec + 2 * (size_t)NB * EPG + (size_t)b * EPG;
        unsigned char* cdst = clrec + (size_t)b * EPG;
        #pragma unroll 2
        for (int j = 0; j < 64; ++j) {
            const int e = t + 128 * j;
            const int r = rowp[e] & (NN - 1);
            const int cl = colp[e] & (NN - 1);
            const int dest = po[r * PSTR + t]++;
            w0[dest] = eap[e * 3 + 0];
            w1[dest] = eap[e * 3 + 1];
            w2[dest] = eap[e * 3 + 2];
            cdst[dest] = (unsigned char)cl;
        }
    }
}

// -------- gconv v20 = v19 with pair-keyed swizzle: one LDS address per edge /
// per-ic (second access at constant +128B/+256B folds into ds offset imm) --------
template<int OUTW, bool IS_L2>
__device__ __forceinline__ void layer_step(
    int rp, int o, int fr, int fkq, int js0, int je0, int je1,
    const float* __restrict__ wp, const unsigned char* __restrict__ clp,
    const float* __restrict__ Wm, const float* __restrict__ Ws,
    const float* __restrict__ bias, const float* __restrict__ wc, // wcomb + layer_row_off*16
    float4* hb4, float* p)
{
    constexpr int NCO = OUTW / 8;              // outputs/thread/row: 8 (L0/L1), 2 (L2)
    const int swz = rp & 7;                    // shared swizzle key for this row pair
    const int base = rp * 32;                  // row0 chunk base (row1 = +16)

    // P1: fused dual-row gather, unrolled x2; one address per edge, 2nd read at +8 chunks
    float ga0[8], ga1[8];
    #pragma unroll
    for (int u = 0; u < 8; ++u) { ga0[u] = 0.f; ga1[u] = 0.f; }
    {
        const int n0 = je0 - js0, n1 = je1 - je0;
        const int nmin = (n0 < n1) ? n0 : n1;
        int i = 0;
        #pragma unroll 1
        for (; i + 2 <= nmin; i += 2) {
            const int cla0 = clp[js0 + i],     clb0 = clp[je0 + i];
            const int cla1 = clp[js0 + i + 1], clb1 = clp[je0 + i + 1];
            const float wa0 = wp[js0 + i],     wb0 = wp[je0 + i];
            const float wa1 = wp[js0 + i + 1], wb1 = wp[je0 + i + 1];
            const int ia0 = cla0 * 16 + (o ^ ((cla0 >> 1) & 7));
            const int ib0 = clb0 * 16 + (o ^ ((clb0 >> 1) & 7));
            const int ia1 = cla1 * 16 + (o ^ ((cla1 >> 1) & 7));
            const int ib1 = clb1 * 16 + (o ^ ((clb1 >> 1) & 7));
            const float4 xa00 = hb4[ia0];
            const float4 xa01 = hb4[ia0 + 8];
            const float4 xb00 = hb4[ib0];
            const float4 xb01 = hb4[ib0 + 8];
            const float4 xa10 = hb4[ia1];
            const float4 xa11 = hb4[ia1 + 8];
            const float4 xb10 = hb4[ib1];
            const float4 xb11 = hb4[ib1 + 8];
            ga0[0] += wa0 * xa00.x + wa1 * xa10.x;
            ga0[1] += wa0 * xa00.y + wa1 * xa10.y;
            ga0[2] += wa0 * xa00.z + wa1 * xa10.z;
            ga0[3] += wa0 * xa00.w + wa1 * xa10.w;
            ga0[4] += wa0 * xa01.x + wa1 * xa11.x;
            ga0[5] += wa0 * xa01.y + wa1 * xa11.y;
            ga0[6] += wa0 * xa01.z + wa1 * xa11.z;
            ga0[7] += wa0 * xa01.w + wa1 * xa11.w;
            ga1[0] += wb0 * xb00.x + wb1 * xb10.x;
            ga1[1] += wb0 * xb00.y + wb1 * xb10.y;
            ga1[2] += wb0 * xb00.z + wb1 * xb10.z;
            ga1[3] += wb0 * xb00.w + wb1 * xb10.w;
            ga1[4] += wb0 * xb01.x + wb1 * xb11.x;
            ga1[5] += wb0 * xb01.y + wb1 * xb11.y;
            ga1[6] += wb0 * xb01.z + wb1 * xb11.z;
            ga1[7] += wb0 * xb01.w + wb1 * xb11.w;
        }
        #pragma unroll 1
        for (; i < nmin; ++i) {
            const int cla = clp[js0 + i];
            const int clb = clp[je0 + i];
            const float wa = wp[js0 + i];
            const float wb = wp[je0 + i];
            const int ia = cla * 16 + (o ^ ((cla >> 1) & 7));
            const int ib = clb * 16 + (o ^ ((clb >> 1) & 7));
            const float4 a0 = hb4[ia];
            const float4 a1 = hb4[ia + 8];
            const float4 bb0 = hb4[ib];
            const float4 bb1 = hb4[ib + 8];
            ga0[0] += wa * a0.x; ga0[1] += wa * a0.y; ga0[2] += wa * a0.z; ga0[3] += wa * a0.w;
            ga0[4] += wa * a1.x; ga0[5] += wa * a1.y; ga0[6] += wa * a1.z; ga0[7] += wa * a1.w;
            ga1[0] += wb * bb0.x; ga1[1] += wb * bb0.y; ga1[2] += wb * bb0.z; ga1[3] += wb * bb0.w;
            ga1[4] += wb * bb1.x; ga1[5] += wb * bb1.y; ga1[6] += wb * bb1.z; ga1[7] += wb * bb1.w;
        }
        #pragma unroll 1
        for (int j = js0 + nmin; j < je0; ++j) {
            const int cl = clp[j];
            const float w = wp[j];
            const int ia = cl * 16 + (o ^ ((cl >> 1) & 7));
            const float4 ha = hb4[ia];
            const float4 hb = hb4[ia + 8];
            ga0[0] += w * ha.x; ga0[1] += w * ha.y; ga0[2] += w * ha.z; ga0[3] += w * ha.w;
            ga0[4] += w * hb.x; ga0[5] += w * hb.y; ga0[6] += w * hb.z; ga0[7] += w * hb.w;
        }
        #pragma unroll 1
        for (int j = je0 + nmin; j < je1; ++j) {
            const int cl = clp[j];
            const float w = wp[j];
            const int ia = cl * 16 + (o ^ ((cl >> 1) & 7));
            const float4 ha = hb4[ia];
            const float4 hb = hb4[ia + 8];
            ga1[0] += w * ha.x; ga1[1] += w * ha.y; ga1[2] += w * ha.z; ga1[3] += w * ha.w;
            ga1[4] += w * hb.x; ga1[5] += w * hb.y; ga1[6] += w * hb.z; ga1[7] += w * hb.w;
        }
    }

    // P2: acc = bias + h@Ws ; one hb address per ic (row1 at +16 chunks)
    const int jA = o * 4;
    const int jB = o * 4 + 32;
    const int j0L2 = o * NCO;
    float acc0[NCO == 8 ? 8 : 2], acc1[NCO == 8 ? 8 : 2];
    if constexpr (NCO == 8) {
        const float4 bv0 = *(const float4*)(bias + jA);
        const float4 bv1 = *(const float4*)(bias + jB);
        acc0[0]=bv0.x; acc0[1]=bv0.y; acc0[2]=bv0.z; acc0[3]=bv0.w;
        acc0[4]=bv1.x; acc0[5]=bv1.y; acc0[6]=bv1.z; acc0[7]=bv1.w;
        #pragma unroll
        for (int u = 0; u < 8; ++u) acc1[u] = acc0[u];
    } else {
        acc0[0] = bias[j0L2]; acc0[1] = bias[j0L2 + 1];
        acc1[0] = acc0[0];    acc1[1] = acc0[1];
    }
    #pragma unroll 1
    for (int ic = 0; ic < 16; ++ic) {
        const int ip = base + ((ic & 8) | ((ic & 7) ^ swz));
        const float4 h40 = hb4[ip];
        const float4 h41 = hb4[ip + 16];
        const float hv0[4] = {h40.x, h40.y, h40.z, h40.w};
        const float hv1[4] = {h41.x, h41.y, h41.z, h41.w};
        #pragma unroll
        for (int u = 0; u < 4; ++u) {
            const float* wr = Ws + (ic * 4 + u) * OUTW;
            const float a0 = hv0[u], a1 = hv1[u];
            if constexpr (NCO == 8) {
                const float4 wa = *(const float4*)(wr + jA);
                const float4 wb = *(const float4*)(wr + jB);
                acc0[0]+=a0*wa.x; acc0[1]+=a0*wa.y; acc0[2]+=a0*wa.z; acc0[3]+=a0*wa.w;
                acc0[4]+=a0*wb.x; acc0[5]+=a0*wb.y; acc0[6]+=a0*wb.z; acc0[7]+=a0*wb.w;
                acc1[0]+=a1*wa.x; acc1[1]+=a1*wa.y; acc1[2]+=a1*wa.z; acc1[3]+=a1*wa.w;
                acc1[4]+=a1*wb.x; acc1[5]+=a1*wb.y; acc1[6]+=a1*wb.z; acc1[7]+=a1*wb.w;
            } else {
                const float2 w2 = *(const float2*)(wr + j0L2);
                acc0[0]+=a0*w2.x; acc0[1]+=a0*w2.y;
                acc1[0]+=a1*w2.x; acc1[1]+=a1*w2.y;
            }
        }
    }
    __syncthreads();                           // [B1] all hb reads (gather + P2) done

    // P3: write agg over h — 4 writes off one base (offsets 0/+8/+16/+24 chunks)
    {
        const int i0 = base + (o ^ swz);
        float4 v;
        v.x = ga0[0]; v.y = ga0[1]; v.z = ga0[2]; v.w = ga0[3]; hb4[i0] = v;
        v.x = ga0[4]; v.y = ga0[5]; v.z = ga0[6]; v.w = ga0[7]; hb4[i0 + 8] = v;
        v.x = ga1[0]; v.y = ga1[1]; v.z = ga1[2]; v.w = ga1[3]; hb4[i0 + 16] = v;
        v.x = ga1[4]; v.y = ga1[5]; v.z = ga1[6]; v.w = ga1[7]; hb4[i0 + 24] = v;
    }
    __syncthreads();                           // [B2] agg visible

    // P4: acc += agg@Wm
    #pragma unroll 1
    for (int ic = 0; ic < 16; ++ic) {
        const int ip = base + ((ic & 8) | ((ic & 7) ^ swz));
        const float4 a40 = hb4[ip];
        const float4 a41 = hb4[ip + 16];
        const float av0[4] = {a40.x, a40.y, a40.z, a40.w};
        const float av1[4] = {a41.x, a41.y, a41.z, a41.w};
        #pragma unroll
        for (int u = 0; u < 4; ++u) {
            const float* wr = Wm + (ic * 4 + u) * OUTW;
            const float a0 = av0[u], a1 = av1[u];
            if constexpr (NCO == 8) {
                const float4 wa = *(const float4*)(wr + jA);
                const float4 wb = *(const float4*)(wr + jB);
                acc0[0]+=a0*wa.x; acc0[1]+=a0*wa.y; acc0[2]+=a0*wa.z; acc0[3]+=a0*wa.w;
                acc0[4]+=a0*wb.x; acc0[5]+=a0*wb.y; acc0[6]+=a0*wb.z; acc0[7]+=a0*wb.w;
                acc1[0]+=a1*wa.x; acc1[1]+=a1*wa.y; acc1[2]+=a1*wa.z; acc1[3]+=a1*wa.w;
                acc1[4]+=a1*wb.x; acc1[5]+=a1*wb.y; acc1[6]+=a1*wb.z; acc1[7]+=a1*wb.w;
            } else {
                const float2 w2 = *(const float2*)(wr + j0L2);
                acc0[0]+=a0*w2.x; acc0[1]+=a0*w2.y;
                acc1[0]+=a1*w2.x; acc1[1]+=a1*w2.y;
            }
        }
    }
    #pragma unroll
    for (int jj = 0; jj < NCO; ++jj) {
        acc0[jj] = fmaxf(acc0[jj], 0.f);
        acc1[jj] = fmaxf(acc1[jj], 0.f);
    }
    __syncthreads();                           // [B3] agg reads done

    // P5: write h_next
    if constexpr (!IS_L2) {
        const int i0 = base + (o ^ swz);
        float4 v;
        v.x = acc0[0]; v.y = acc0[1]; v.z = acc0[2]; v.w = acc0[3]; hb4[i0] = v;
        v.x = acc0[4]; v.y = acc0[5]; v.z = acc0[6]; v.w = acc0[7]; hb4[i0 + 8] = v;
        v.x = acc1[0]; v.y = acc1[1]; v.z = acc1[2]; v.w = acc1[3]; hb4[i0 + 16] = v;
        v.x = acc1[4]; v.y = acc1[5]; v.z = acc1[6]; v.w = acc1[7]; hb4[i0 + 24] = v;
    } else {
        float* hbf = (float*)hb4;
        const int cc = o >> 1, off = (o & 1) * 2;
        const int ph = cc ^ swz;               // cc<4, swz<8 -> ph<8 (chunks 0..7)
        float* p0 = hbf + (base + ph) * 4 + off;
        float* p1 = hbf + (base + 16 + ph) * 4 + off;
        p0[0] = acc0[0]; p0[1] = acc0[1];
        p1[0] = acc1[0]; p1[1] = acc1[1];
    }
    __syncthreads();                           // [B4] h_next visible

    // FC: thread (fr,fkq) accumulates p[4] += h_next[fr][:] @ Wc[:, fkq*4..+4]
    {
        const int rb = fr * 16, rs = (fr >> 1) & 7;
        if constexpr (!IS_L2) {
            #pragma unroll 2
            for (int c4 = 0; c4 < 16; ++c4) {
                const float4 v4 = hb4[rb + ((c4 & 8) | ((c4 & 7) ^ rs))];
                const float vv[4] = {v4.x, v4.y, v4.z, v4.w};
                #pragma unroll
                for (int e = 0; e < 4; ++e) {
                    const float4 w4 = *(const float4*)(wc + (c4 * 4 + e) * 16 + fkq * 4);
                    p[0] += vv[e] * w4.x; p[1] += vv[e] * w4.y;
                    p[2] += vv[e] * w4.z; p[3] += vv[e] * w4.w;
                }
            }
        } else {
            #pragma unroll 2
            for (int c4 = 0; c4 < 4; ++c4) {
                const float4 v4 = hb4[rb + (c4 ^ rs)];
                const float vv[4] = {v4.x, v4.y, v4.z, v4.w};
                #pragma unroll
                for (int e = 0; e < 4; ++e) {
                    const float4 w4 = *(const float4*)(wc + (c4 * 4 + e) * 16 + fkq * 4);
                    p[0] += vv[e] * w4.x; p[1] += vv[e] * w4.y;
                    p[2] += vv[e] * w4.z; p[3] += vv[e] * w4.w;
                }
            }
        }
    }
}

__launch_bounds__(1024)
__global__ void gconv_kernel(
    const float* __restrict__ x,
    const float* __restrict__ x_to_pool,
    const float* __restrict__ Wm0, const float* __restrict__ Ws0, const float* __restrict__ b0,
    const float* __restrict__ Wm1, const float* __restrict__ Ws1, const float* __restrict__ b1,
    const float* __restrict__ Wm2, const float* __restrict__ Ws2, const float* __restrict__ b2,
    const float* __restrict__ wcomb, const float* __restrict__ bcomb,
    const float* __restrict__ wrec, const unsigned char* __restrict__ clrec,
    const int* __restrict__ indptr,
    float* __restrict__ out, float* __restrict__ entpart, float* __restrict__ modpart)
{
    __shared__ float4 hb4[4096];       // exactly 64 KB — reused by the pool epilogue
    float* hbf = (float*)hb4;
    const int t = threadIdx.x;
    const int bid = blockIdx.x;
    const int d = bid >> 8;
    const int b = bid & (NB - 1);
    const int rp = t >> 3;         // row pair
    const int o = t & 7;           // chunk owner (chunks o, o+8)
    const int fr = t >> 2;         // FC row
    const int fkq = t & 3;         // FC k-quad
    const int lane = t & 63;
    const int wave = t >> 6;

    // stage x -> hb (pair-keyed swizzle)
    {
        const float4* xv = (const float4*)(x + (size_t)b * NN * HID);
        #pragma unroll
        for (int it = 0; it < 4; ++it) {
            const int idx = t + it * 1024;
            const int nrow = idx >> 4, c = idx & 15;
            const int ph = (c & 8) | ((c & 7) ^ ((nrow >> 1) & 7));
            hb4[nrow * 16 + ph] = xv[idx];
        }
    }
    float p[4] = {0.f, 0.f, 0.f, 0.f};
    __syncthreads();   // [B0]

    const float* wp = wrec + (size_t)d * NB * EPG + (size_t)b * EPG;
    const unsigned char* clp = clrec + (size_t)b * EPG;
    const int* ipb = indptr + b * 257;
    const int js0 = ipb[rp * 2];
    const int je0 = ipb[rp * 2 + 1];
    const int je1 = ipb[rp * 2 + 2];

    layer_step<64, false>(rp, o, fr, fkq, js0, je0, je1, wp, clp, Wm0 + d*HID*HID,
                          Ws0 + d*HID*HID, b0 + d*HID, wcomb,          hb4, p);
    layer_step<64, false>(rp, o, fr, fkq, js0, je0, je1, wp, clp, Wm1 + d*HID*HID,
                          Ws1 + d*HID*HID, b1 + d*HID, wcomb + 64*16,  hb4, p);
    layer_step<16, true >(rp, o, fr, fkq, js0, je0, je1, wp, clp, Wm2 + d*HID*KK,
                          Ws2 + d*HID*KK,  b2 + d*KK,  wcomb + 128*16, hb4, p);

    __syncthreads();   // [B5] FC reads done — hb reusable
    {
        float* dst = hbf + SL_OFF + fr * 20 + fkq * 4;
        dst[0] = p[0]; dst[1] = p[1]; dst[2] = p[2]; dst[3] = p[3];
    }
    __syncthreads();   // [B6] logits visible

    // softmax + entropy (t<256); s overwrites logits region; s also -> out
    float ent_local = 0.f;
    if (t < 256) {
        const int rr = t;
        float* Lr = hbf + SL_OFF + rr * 20;
        float logits[KK];
        #pragma unroll
        for (int k = 0; k < KK; ++k) logits[k] = Lr[k] + bcomb[k];
        float m = logits[0];
        #pragma unroll
        for (int k = 1; k < KK; ++k) m = fmaxf(m, logits[k]);
        float sum = 0.f, sv[KK];
        #pragma unroll
        for (int k = 0; k < KK; ++k) { sv[k] = expf(logits[k] - m); sum += sv[k]; }
        const float inv = 1.f / sum;
        float4* sp4 = (float4*)(out + S_OFF + ((size_t)(d * NB + b) * NN + rr) * KK);
        #pragma unroll
        for (int q4 = 0; q4 < 4; ++q4) {
            float4 v;
            const float s0 = sv[q4*4+0] * inv, s1 = sv[q4*4+1] * inv;
            const float s2 = sv[q4*4+2] * inv, s3 = sv[q4*4+3] * inv;
            v.x = s0; v.y = s1; v.z = s2; v.w = s3;
            sp4[q4] = v;
            *(float4*)(Lr + q4 * 4) = v;          // s into LDS
            ent_local -= s0 * logf(s0 + 1e-15f) + s1 * logf(s1 + 1e-15f)
                       + s2 * logf(s2 + 1e-15f) + s3 * logf(s3 + 1e-15f);
        }
    }
    #pragma unroll
    for (int off = 32; off; off >>= 1) ent_local += __shfl_down(ent_local, off);
    if (lane == 0) hbf[ERED_OFF + wave] = ent_local;
    __syncthreads();   // [B7] s + ent partials visible
    if (t == 0) {
        float s = 0.f;
        #pragma unroll
        for (int w = 0; w < 16; ++w) s += hbf[ERED_OFF + w];
        entpart[bid] = s;
    }

    // ---- fused pool ----
    // Phase A: G = A*s (thread=(row pr, kquad pkq)) + modularity partial, unrolled x2
    {
        const int pr = t >> 2, pkq = t & 3;
        const int pjs = ipb[pr], pje = ipb[pr + 1];
        const float4 sq = *(const float4*)(hbf + SL_OFF + pr * 20 + pkq * 4);
        float g0 = 0.f, g1 = 0.f, g2 = 0.f, g3 = 0.f;
        float modp = 0.f;
        int j = pjs;
        #pragma unroll 1
        for (; j + 2 <= pje; j += 2) {
            const int cl0 = clp[j], cl1 = clp[j + 1];
            const float w0 = wp[j], w1 = wp[j + 1];
            const float4 sa = *(const float4*)(hbf + SL_OFF + cl0 * 20 + pkq * 4);
            const float4 sb = *(const float4*)(hbf + SL_OFF + cl1 * 20 + pkq * 4);
            g0 += w0 * sa.x + w1 * sb.x; g1 += w0 * sa.y + w1 * sb.y;
            g2 += w0 * sa.z + w1 * sb.z; g3 += w0 * sa.w + w1 * sb.w;
            const float a0 = sq.x - sa.x, a1 = sq.y - sa.y, a2 = sq.z - sa.z, a3 = sq.w - sa.w;
            const float b0v = sq.x - sb.x, b1v = sq.y - sb.y, b2v = sq.z - sb.z, b3v = sq.w - sb.w;
            modp += w0 * (a0*a0 + a1*a1 + a2*a2 + a3*a3)
                  + w1 * (b0v*b0v + b1v*b1v + b2v*b2v + b3v*b3v);
        }
        if (j < pje) {
            const int cl = clp[j];
            const float w = wp[j];
            const float4 sc4 = *(const float4*)(hbf + SL_OFF + cl * 20 + pkq * 4);
            g0 += w * sc4.x; g1 += w * sc4.y; g2 += w * sc4.z; g3 += w * sc4.w;
            const float d0 = sq.x - sc4.x, d1 = sq.y - sc4.y;
            const float d2 = sq.z - sc4.z, d3 = sq.w - sc4.w;
            modp += w * (d0*d0 + d1*d1 + d2*d2 + d3*d3);
        }
        float4 gv; gv.x = g0; gv.y = g1; gv.z = g2; gv.w = g3;
        *(float4*)(hbf + GL_OFF + pr * 20 + pkq * 4) = gv;
        #pragma unroll
        for (int off = 32; off; off >>= 1) modp += __shfl_down(modp, off);
        if (lane == 0) hbf[MRED_OFF + wave] = modp;
    }
    __syncthreads();   // [B8] G + mod partials visible
    if (t == 0) {
        float s = 0.f;
        #pragma unroll
        for (int w = 0; w < 16; ++w) s += hbf[MRED_OFF + w];
        modpart[bid] = s;
    }

    // Phase B: padj partials — thread (q=t>>8, k=(t>>4)&15, l=t&15) over rows [q*64,q*64+64)
    {
        const int q = t >> 8, kl = t & 255;
        const int k = kl >> 4, l = kl & 15;
        float acc = 0.f;
        const int r0 = q * 64;
        #pragma unroll 4
        for (int r = r0; r < r0 + 64; ++r)
            acc += hbf[SL_OFF + r * 20 + k] * hbf[GL_OFF + r * 20 + l];
        hbf[PJW_OFF + q * 256 + kl] = acc;
    }

    // Phase C: px partials — thread (rg=t>>8, kg=(t>>6)&3, f=t&63) over rows [rg*64,+64)
    {
        const int rg = t >> 8, kg = (t >> 6) & 3, f = t & 63;
        const float* xp = x_to_pool + (size_t)b * NN * (64 * DIMS) + f * DIMS + d;
        float xa0 = 0.f, xa1 = 0.f, xa2 = 0.f, xa3 = 0.f;
        const int n0 = rg * 64;
        #pragma unroll 4
        for (int n = n0; n < n0 + 64; ++n) {
            const float xv = xp[(size_t)n * (64 * DIMS)];
            const float4 s4 = *(const float4*)(hbf + SL_OFF + n * 20 + kg * 4);
            xa0 += xv * s4.x; xa1 += xv * s4.y; xa2 += xv * s4.z; xa3 += xv * s4.w;
        }
        float4 v; v.x = xa0; v.y = xa1; v.z = xa2; v.w = xa3;
        *(float4*)(hbf + PXP_OFF + ((rg * 4 + kg) * 64 + f) * 4) = v;
    }
    __syncthreads();   // [B9] padj + px partials visible

    // Phase D merges (deterministic fixed-order sums)
    if (t < 256) {     // pea: (k,l) = (t>>4, t&15)
        const float v = (hbf[PJW_OFF + t] + hbf[PJW_OFF + 256 + t]
                       + hbf[PJW_OFF + 512 + t] + hbf[PJW_OFF + 768 + t]) * (1.f / 256.f);
        out[PEA_OFF + (size_t)((b * KK + (t >> 4)) * KK + (t & 15)) * DIMS + d] = v;
    }
    {                  // px: (k,f) = (t>>6, t&63)
        const int k = t >> 6, f = t & 63;
        const int kg = k >> 2, e = k & 3;
        float s = 0.f;
        #pragma unroll
        for (int rg = 0; rg < 4; ++rg)
            s += hbf[PXP_OFF + ((rg * 4 + kg) * 64 + f) * 4 + e];
        out[PX_OFF + ((size_t)((b * KK + k) * 64) + f) * DIMS + d] = s * (1.f / 16.f);
    }
}

__global__ void aux_kernel(float* __restrict__ out)
{
    const int idx = blockIdx.x * 256 + threadIdx.x;
    if (idx < 2 * NTOT) {
        const int r = idx & (NTOT - 1);
        const int bb = r >> 8;
        const int j = r & 255;
        const int v = (idx < NTOT) ? (bb * KK + (j >> 4)) : (bb * KK + (j & 15));
        out[PEI_OFF + idx] = (float)v;
    } else if (idx < 2 * NTOT + NB * KK) {
        const int i = idx - 2 * NTOT;
        out[PB_OFF + i] = (float)(i >> 4);
    }
}

__global__ void loss_kernel(const float* __restrict__ entpart,
                            const float* __restrict__ modpart,
                            float* __restrict__ out)
{
    const int tid = threadIdx.x;
    float e = 0.f, m = 0.f;
    for (int i = tid; i < DIMS * NB; i += 256) { e += entpart[i]; m += modpart[i]; }
    #pragma unroll
    for (int off = 32; off; off >>= 1) { e += __shfl_down(e, off); m += __shfl_down(m, off); }
    __shared__ float er[4], mr[4];
    const int wave = tid >> 6, lane = tid & 63;
    if (lane == 0) { er[wave] = e; mr[wave] = m; }
    __syncthreads();
    if (tid == 0) {
        const float es = er[0] + er[1] + er[2] + er[3];
        const float ms = mr[0] + mr[1] + mr[2] + mr[3];
        out[LOSS_OFF] = ms / (float)NE + es / (float)(DIMS * NTOT);
    }
}

extern "C" void kernel_launch(void* const* d_in, const int* in_sizes, int n_in,
                              void* d_out, int out_size, void* d_ws, size_t ws_size,
                              hipStream_t stream)
{
    const float* x         = (const float*)d_in[0];
    const float* edge_attr = (const float*)d_in[1];
    const float* x_to_pool = (const float*)d_in[2];
    const float* Wm0 = (const float*)d_in[3];
    const float* Ws0 = (const float*)d_in[4];
    const float* b0  = (const float*)d_in[5];
    const float* Wm1 = (const float*)d_in[6];
    const float* Ws1 = (const float*)d_in[7];
    const float* b1  = (const float*)d_in[8];
    const float* Wm2 = (const float*)d_in[9];
    const float* Ws2 = (const float*)d_in[10];
    const float* b2  = (const float*)d_in[11];
    const float* fcW1= (const float*)d_in[12];
    const float* fcb1= (const float*)d_in[13];
    const float* fcW2= (const float*)d_in[14];
    const float* fcb2= (const float*)d_in[15];
    const int* edge_index = (const int*)d_in[16];
    float* out = (float*)d_out;
    char* ws = (char*)d_ws;
    float*         wrec  = (float*)(ws + WREC_WS);
    unsigned char* clrec = (unsigned char*)(ws + CLREC_WS);
    int*           iptr  = (int*)(ws + IPTR_WS);
    float*         entpart = (float*)(ws + ENT_WS);
    float*         modpart = (float*)(ws + MOD_WS);
    float*         wc    = (float*)(ws + WC_WS);
    float*         bc    = (float*)(ws + BC_WS);

    csr_build<<<dim3(NB), dim3(256), 0, stream>>>(edge_index, edge_attr, wrec, clrec, iptr);
    fc_combine<<<dim3(1), dim3(256), 0, stream>>>(fcW1, fcb1, fcW2, fcb2, wc, bc);
    gconv_kernel<<<dim3(DIMS * NB), dim3(1024), 0, stream>>>(
        x, x_to_pool, Wm0, Ws0, b0, Wm1, Ws1, b1, Wm2, Ws2, b2,
        wc, bc, wrec, clrec, iptr, out, entpart, modpart);
    aux_kernel<<<dim3((2 * NTOT + NB * KK + 255) / 256), dim3(256), 0, stream>>>(out);
    loss_kernel<<<dim3(1), dim3(256), 0, stream>>>(entpart, modpart, out);
}

// Round 21
// 561.189 us; speedup vs baseline: 1.0076x; 1.0076x over previous
//
#include <hip/hip_runtime.h>

#define DIMS 3
#define NB 256
#define NN 256
#define KK 16
#define HID 64
#define EPG 8192
#define NTOT (NB*NN)
#define NE (NB*EPG)

// d_out layout (flat concat of reference outputs, all as float)
#define PX_OFF   0          // (B*K, F, DIMS)           = 786432
#define PEI_OFF  786432     // (2, B*K*K)               = 131072
#define PEA_OFF  917504     // (B*K*K, DIMS)            = 196608
#define PB_OFF   1114112    // (B*K,)                   = 4096
#define LOSS_OFF 1118208    // scalar
#define S_OFF    1118209    // (DIMS, B, N, K)          = 3145728

// d_ws layout (bytes) — total ~27.5 MB
#define WREC_WS  0                 // float[3][NB*EPG] per-d edge weight (CSR order) = 24 MB
#define CLREC_WS 25165824          // uchar[NB*EPG] col-local index
#define IPTR_WS  27262976          // int[NB*257]
#define ENT_WS   27526144          // float[768]
#define MOD_WS   27529216          // float[768]
#define WC_WS    27532288          // float[144*16]  (fcW1 @ fcW2)
#define BC_WS    27541504          // float[16]      (fcb1 @ fcW2 + fcb2)

// Pool-epilogue regions live in the (dead) agg buffer ab (16384 floats):
#define SL_OFF   0         // s tile      [256][20]  -> [0, 5120)
#define GL_OFF   5120      // G tile      [256][20]  -> [5120, 10240)
#define PXP_OFF  10240     // px partials [16][64][4]-> [10240, 14336)
#define PJW_OFF  14336     // padj part.  [4][256]   -> [14336, 15360)
#define MRED_OFF 15360     // mod red     [16]
#define ERED_OFF 15380     // ent red     [16]

// h/agg layout map: logical (row, chunk c in 0..15) stored at
//   phys(c,row) = (c&8) | ((c&7) ^ ((row>>1)&7))  (pair-keyed swizzle)

// ---------------- combined FC weights: Wc = fcW1@fcW2, bc = fcb1@fcW2+fcb2 ----------------
__global__ void fc_combine(const float* __restrict__ fcW1, const float* __restrict__ fcb1,
                           const float* __restrict__ fcW2, const float* __restrict__ fcb2,
                           float* __restrict__ wc, float* __restrict__ bc)
{
    const int t = threadIdx.x;
    for (int idx = t; idx < 144 * 16; idx += 256) {
        const int i = idx >> 4, k = idx & 15;
        float s = 0.f;
        for (int q = 0; q < 50; ++q) s += fcW1[i * 50 + q] * fcW2[q * 16 + k];
        wc[idx] = s;
    }
    if (t < 16) {
        float s = fcb2[t];
        for (int q = 0; q < 50; ++q) s += fcb1[q] * fcW2[q * 16 + t];
        bc[t] = s;
    }
}

// ------- CSR build: parallel deterministic counting sort (strided chunks) -------
#define HSTR 132
#define PSTR 129
__launch_bounds__(256)
__global__ void csr_build(const int* __restrict__ edge_index,
                          const float* __restrict__ edge_attr,
                          float* __restrict__ wrec, unsigned char* __restrict__ clrec,
                          int* __restrict__ indptr)
{
    __shared__ unsigned char  h[256 * HSTR];    // 33.8 KB
    __shared__ unsigned short po[256 * PSTR];   // 66.0 KB
    __shared__ int sc[256];
    const int b = blockIdx.x;
    const int t = threadIdx.x;
    const int* rowp = edge_index + (size_t)b * EPG;
    const int* colp = edge_index + (size_t)NB * EPG + (size_t)b * EPG;

    for (int i = t; i < 256 * HSTR / 4; i += 256) ((unsigned int*)h)[i] = 0u;
    __syncthreads();

    if (t < 128) {
        #pragma unroll 4
        for (int j = 0; j < 64; ++j) {
            const int r = rowp[t + 128 * j] & (NN - 1);
            h[r * HSTR + t]++;
        }
    }
    __syncthreads();

    int tot;
    {
        int s = 0;
        const unsigned int* hr = (const unsigned int*)(h + t * HSTR);
        #pragma unroll
        for (int c4 = 0; c4 < HSTR / 4; ++c4) {
            const unsigned int v = hr[c4];
            s += (v & 255) + ((v >> 8) & 255) + ((v >> 16) & 255) + (v >> 24);
        }
        tot = s;
        sc[t] = s;
    }
    __syncthreads();
    for (int ofs = 1; ofs < 256; ofs <<= 1) {
        int v = (t >= ofs) ? sc[t - ofs] : 0;
        __syncthreads();
        sc[t] += v;
        __syncthreads();
    }
    const int start = sc[t] - tot;
    indptr[b * 257 + t] = start;
    if (t == 255) indptr[b * 257 + 256] = EPG;

    {
        int run = start;
        #pragma unroll 4
        for (int c = 0; c < 128; ++c) {
            po[t * PSTR + c] = (unsigned short)run;
            run += h[t * HSTR + c];
        }
    }
    __syncthreads();

    if (t < 128) {
        const float* eap = edge_attr + (size_t)b * EPG * 3;
        float* w0 = wrec + (size_t)b * EPG;
        float* w1 = wrec + (size_t)NB * EPG + (size_t)b * EPG;
        float* w2 = wrec + 2 * (size_t)NB * EPG + (size_t)b * EPG;
        unsigned char* cdst = clrec + (size_t)b * EPG;
        #pragma unroll 2
        for (int j = 0; j < 64; ++j) {
            const int e = t + 128 * j;
            const int r = rowp[e] & (NN - 1);
            const int cl = colp[e] & (NN - 1);
            const int dest = po[r * PSTR + t]++;
            w0[dest] = eap[e * 3 + 0];
            w1[dest] = eap[e * 3 + 1];
            w2[dest] = eap[e * 3 + 2];
            cdst[dest] = (unsigned char)cl;
        }
    }
}

// -------- gconv v21: TWO LDS buffers (hb + ab, 128 KB — occupancy is 1 block/CU at any
// LDS, measured R11/R15) -> agg-overwrite dance removed, 2 barriers/layer instead of 4:
//   P1 gather (read hb) + write ab | P2 acc=bias+h@Ws (read hb) | B1 |
//   P4 acc+=ab@Wm | relu | P5 h_next->hb | B2 | FC (read hb)
// Pool epilogue relocated into the dead ab buffer. --------
template<int OUTW, bool IS_L2>
__device__ __forceinline__ void layer_step(
    int rp, int o, int fr, int fkq, int js0, int je0, int je1,
    const float* __restrict__ wp, const unsigned char* __restrict__ clp,
    const float* __restrict__ Wm, const float* __restrict__ Ws,
    const float* __restrict__ bias, const float* __restrict__ wc, // wcomb + layer_row_off*16
    float4* hb4, float4* ab4, float* p)
{
    constexpr int NCO = OUTW / 8;              // outputs/thread/row: 8 (L0/L1), 2 (L2)
    const int swz = rp & 7;                    // shared swizzle key for this row pair
    const int base = rp * 32;                  // row0 chunk base (row1 = +16)

    // P1: fused dual-row gather, unrolled x2 (reads hb)
    float ga0[8], ga1[8];
    #pragma unroll
    for (int u = 0; u < 8; ++u) { ga0[u] = 0.f; ga1[u] = 0.f; }
    {
        const int n0 = je0 - js0, n1 = je1 - je0;
        const int nmin = (n0 < n1) ? n0 : n1;
        int i = 0;
        #pragma unroll 1
        for (; i + 2 <= nmin; i += 2) {
            const int cla0 = clp[js0 + i],     clb0 = clp[je0 + i];
            const int cla1 = clp[js0 + i + 1], clb1 = clp[je0 + i + 1];
            const float wa0 = wp[js0 + i],     wb0 = wp[je0 + i];
            const float wa1 = wp[js0 + i + 1], wb1 = wp[je0 + i + 1];
            const int ia0 = cla0 * 16 + (o ^ ((cla0 >> 1) & 7));
            const int ib0 = clb0 * 16 + (o ^ ((clb0 >> 1) & 7));
            const int ia1 = cla1 * 16 + (o ^ ((cla1 >> 1) & 7));
            const int ib1 = clb1 * 16 + (o ^ ((clb1 >> 1) & 7));
            const float4 xa00 = hb4[ia0];
            const float4 xa01 = hb4[ia0 + 8];
            const float4 xb00 = hb4[ib0];
            const float4 xb01 = hb4[ib0 + 8];
            const float4 xa10 = hb4[ia1];
            const float4 xa11 = hb4[ia1 + 8];
            const float4 xb10 = hb4[ib1];
            const float4 xb11 = hb4[ib1 + 8];
            ga0[0] += wa0 * xa00.x + wa1 * xa10.x;
            ga0[1] += wa0 * xa00.y + wa1 * xa10.y;
            ga0[2] += wa0 * xa00.z + wa1 * xa10.z;
            ga0[3] += wa0 * xa00.w + wa1 * xa10.w;
            ga0[4] += wa0 * xa01.x + wa1 * xa11.x;
            ga0[5] += wa0 * xa01.y + wa1 * xa11.y;
            ga0[6] += wa0 * xa01.z + wa1 * xa11.z;
            ga0[7] += wa0 * xa01.w + wa1 * xa11.w;
            ga1[0] += wb0 * xb00.x + wb1 * xb10.x;
            ga1[1] += wb0 * xb00.y + wb1 * xb10.y;
            ga1[2] += wb0 * xb00.z + wb1 * xb10.z;
            ga1[3] += wb0 * xb00.w + wb1 * xb10.w;
            ga1[4] += wb0 * xb01.x + wb1 * xb11.x;
            ga1[5] += wb0 * xb01.y + wb1 * xb11.y;
            ga1[6] += wb0 * xb01.z + wb1 * xb11.z;
            ga1[7] += wb0 * xb01.w + wb1 * xb11.w;
        }
        #pragma unroll 1
        for (; i < nmin; ++i) {
            const int cla = clp[js0 + i];
            const int clb = clp[je0 + i];
            const float wa = wp[js0 + i];
            const float wb = wp[je0 + i];
            const int ia = cla * 16 + (o ^ ((cla >> 1) & 7));
            const int ib = clb * 16 + (o ^ ((clb >> 1) & 7));
            const float4 a0 = hb4[ia];
            const float4 a1 = hb4[ia + 8];
            const float4 bb0 = hb4[ib];
            const float4 bb1 = hb4[ib + 8];
            ga0[0] += wa * a0.x; ga0[1] += wa * a0.y; ga0[2] += wa * a0.z; ga0[3] += wa * a0.w;
            ga0[4] += wa * a1.x; ga0[5] += wa * a1.y; ga0[6] += wa * a1.z; ga0[7] += wa * a1.w;
            ga1[0] += wb * bb0.x; ga1[1] += wb * bb0.y; ga1[2] += wb * bb0.z; ga1[3] += wb * bb0.w;
            ga1[4] += wb * bb1.x; ga1[5] += wb * bb1.y; ga1[6] += wb * bb1.z; ga1[7] += wb * bb1.w;
        }
        #pragma unroll 1
        for (int j = js0 + nmin; j < je0; ++j) {
            const int cl = clp[j];
            const float w = wp[j];
            const int ia = cl * 16 + (o ^ ((cl >> 1) & 7));
            const float4 ha = hb4[ia];
            const float4 hb = hb4[ia + 8];
            ga0[0] += w * ha.x; ga0[1] += w * ha.y; ga0[2] += w * ha.z; ga0[3] += w * ha.w;
            ga0[4] += w * hb.x; ga0[5] += w * hb.y; ga0[6] += w * hb.z; ga0[7] += w * hb.w;
        }
        #pragma unroll 1
        for (int j = je0 + nmin; j < je1; ++j) {
            const int cl = clp[j];
            const float w = wp[j];
            const int ia = cl * 16 + (o ^ ((cl >> 1) & 7));
            const float4 ha = hb4[ia];
            const float4 hb = hb4[ia + 8];
            ga1[0] += w * ha.x; ga1[1] += w * ha.y; ga1[2] += w * ha.z; ga1[3] += w * ha.w;
            ga1[4] += w * hb.x; ga1[5] += w * hb.y; ga1[6] += w * hb.z; ga1[7] += w * hb.w;
        }
    }
    // write agg -> ab (own cells; overlaps P2; fenced by B1 before P4 reads)
    {
        const int i0 = base + (o ^ swz);
        float4 v;
        v.x = ga0[0]; v.y = ga0[1]; v.z = ga0[2]; v.w = ga0[3]; ab4[i0] = v;
        v.x = ga0[4]; v.y = ga0[5]; v.z = ga0[6]; v.w = ga0[7]; ab4[i0 + 8] = v;
        v.x = ga1[0]; v.y = ga1[1]; v.z = ga1[2]; v.w = ga1[3]; ab4[i0 + 16] = v;
        v.x = ga1[4]; v.y = ga1[5]; v.z = ga1[6]; v.w = ga1[7]; ab4[i0 + 24] = v;
    }

    // P2: acc = bias + h@Ws (reads hb)
    const int jA = o * 4;
    const int jB = o * 4 + 32;
    const int j0L2 = o * NCO;
    float acc0[NCO == 8 ? 8 : 2], acc1[NCO == 8 ? 8 : 2];
    if constexpr (NCO == 8) {
        const float4 bv0 = *(const float4*)(bias + jA);
        const float4 bv1 = *(const float4*)(bias + jB);
        acc0[0]=bv0.x; acc0[1]=bv0.y; acc0[2]=bv0.z; acc0[3]=bv0.w;
        acc0[4]=bv1.x; acc0[5]=bv1.y; acc0[6]=bv1.z; acc0[7]=bv1.w;
        #pragma unroll
        for (int u = 0; u < 8; ++u) acc1[u] = acc0[u];
    } else {
        acc0[0] = bias[j0L2]; acc0[1] = bias[j0L2 + 1];
        acc1[0] = acc0[0];    acc1[1] = acc0[1];
    }
    #pragma unroll 1
    for (int ic = 0; ic < 16; ++ic) {
        const int ip = base + ((ic & 8) | ((ic & 7) ^ swz));
        const float4 h40 = hb4[ip];
        const float4 h41 = hb4[ip + 16];
        const float hv0[4] = {h40.x, h40.y, h40.z, h40.w};
        const float hv1[4] = {h41.x, h41.y, h41.z, h41.w};
        #pragma unroll
        for (int u = 0; u < 4; ++u) {
            const float* wr = Ws + (ic * 4 + u) * OUTW;
            const float a0 = hv0[u], a1 = hv1[u];
            if constexpr (NCO == 8) {
                const float4 wa = *(const float4*)(wr + jA);
                const float4 wb = *(const float4*)(wr + jB);
                acc0[0]+=a0*wa.x; acc0[1]+=a0*wa.y; acc0[2]+=a0*wa.z; acc0[3]+=a0*wa.w;
                acc0[4]+=a0*wb.x; acc0[5]+=a0*wb.y; acc0[6]+=a0*wb.z; acc0[7]+=a0*wb.w;
                acc1[0]+=a1*wa.x; acc1[1]+=a1*wa.y; acc1[2]+=a1*wa.z; acc1[3]+=a1*wa.w;
                acc1[4]+=a1*wb.x; acc1[5]+=a1*wb.y; acc1[6]+=a1*wb.z; acc1[7]+=a1*wb.w;
            } else {
                const float2 w2 = *(const float2*)(wr + j0L2);
                acc0[0]+=a0*w2.x; acc0[1]+=a0*w2.y;
                acc1[0]+=a1*w2.x; acc1[1]+=a1*w2.y;
            }
        }
    }
    __syncthreads();   // [B1] ab writes visible; all hb reads of this layer done

    // P4: acc += ab@Wm
    #pragma unroll 1
    for (int ic = 0; ic < 16; ++ic) {
        const int ip = base + ((ic & 8) | ((ic & 7) ^ swz));
        const float4 a40 = ab4[ip];
        const float4 a41 = ab4[ip + 16];
        const float av0[4] = {a40.x, a40.y, a40.z, a40.w};
        const float av1[4] = {a41.x, a41.y, a41.z, a41.w};
        #pragma unroll
        for (int u = 0; u < 4; ++u) {
            const float* wr = Wm + (ic * 4 + u) * OUTW;
            const float a0 = av0[u], a1 = av1[u];
            if constexpr (NCO == 8) {
                const float4 wa = *(const float4*)(wr + jA);
                const float4 wb = *(const float4*)(wr + jB);
                acc0[0]+=a0*wa.x; acc0[1]+=a0*wa.y; acc0[2]+=a0*wa.z; acc0[3]+=a0*wa.w;
                acc0[4]+=a0*wb.x; acc0[5]+=a0*wb.y; acc0[6]+=a0*wb.z; acc0[7]+=a0*wb.w;
                acc1[0]+=a1*wa.x; acc1[1]+=a1*wa.y; acc1[2]+=a1*wa.z; acc1[3]+=a1*wa.w;
                acc1[4]+=a1*wb.x; acc1[5]+=a1*wb.y; acc1[6]+=a1*wb.z; acc1[7]+=a1*wb.w;
            } else {
                const float2 w2 = *(const float2*)(wr + j0L2);
                acc0[0]+=a0*w2.x; acc0[1]+=a0*w2.y;
                acc1[0]+=a1*w2.x; acc1[1]+=a1*w2.y;
            }
        }
    }
    #pragma unroll
    for (int jj = 0; jj < NCO; ++jj) {
        acc0[jj] = fmaxf(acc0[jj], 0.f);
        acc1[jj] = fmaxf(acc1[jj], 0.f);
    }

    // P5: write h_next -> hb (own cells; prior hb reads fenced by B1)
    if constexpr (!IS_L2) {
        const int i0 = base + (o ^ swz);
        float4 v;
        v.x = acc0[0]; v.y = acc0[1]; v.z = acc0[2]; v.w = acc0[3]; hb4[i0] = v;
        v.x = acc0[4]; v.y = acc0[5]; v.z = acc0[6]; v.w = acc0[7]; hb4[i0 + 8] = v;
        v.x = acc1[0]; v.y = acc1[1]; v.z = acc1[2]; v.w = acc1[3]; hb4[i0 + 16] = v;
        v.x = acc1[4]; v.y = acc1[5]; v.z = acc1[6]; v.w = acc1[7]; hb4[i0 + 24] = v;
    } else {
        float* hbf = (float*)hb4;
        const int cc = o >> 1, off = (o & 1) * 2;
        const int ph = cc ^ swz;
        float* p0 = hbf + (base + ph) * 4 + off;
        float* p1 = hbf + (base + 16 + ph) * 4 + off;
        p0[0] = acc0[0]; p0[1] = acc0[1];
        p1[0] = acc1[0]; p1[1] = acc1[1];
    }
    __syncthreads();   // [B2] h_next visible; ab reads done

    // FC: thread (fr,fkq) accumulates p[4] += h_next[fr][:] @ Wc[:, fkq*4..+4]
    {
        const int rb = fr * 16, rs = (fr >> 1) & 7;
        if constexpr (!IS_L2) {
            #pragma unroll 2
            for (int c4 = 0; c4 < 16; ++c4) {
                const float4 v4 = hb4[rb + ((c4 & 8) | ((c4 & 7) ^ rs))];
                const float vv[4] = {v4.x, v4.y, v4.z, v4.w};
                #pragma unroll
                for (int e = 0; e < 4; ++e) {
                    const float4 w4 = *(const float4*)(wc + (c4 * 4 + e) * 16 + fkq * 4);
                    p[0] += vv[e] * w4.x; p[1] += vv[e] * w4.y;
                    p[2] += vv[e] * w4.z; p[3] += vv[e] * w4.w;
                }
            }
        } else {
            #pragma unroll 2
            for (int c4 = 0; c4 < 4; ++c4) {
                const float4 v4 = hb4[rb + (c4 ^ rs)];
                const float vv[4] = {v4.x, v4.y, v4.z, v4.w};
                #pragma unroll
                for (int e = 0; e < 4; ++e) {
                    const float4 w4 = *(const float4*)(wc + (c4 * 4 + e) * 16 + fkq * 4);
                    p[0] += vv[e] * w4.x; p[1] += vv[e] * w4.y;
                    p[2] += vv[e] * w4.z; p[3] += vv[e] * w4.w;
                }
            }
        }
    }
    // no trailing barrier: next layer reads hb (safe concurrent) and writes ab
    // (this layer's ab reads fenced by B2).
}

__launch_bounds__(1024)
__global__ void gconv_kernel(
    const float* __restrict__ x,
    const float* __restrict__ x_to_pool,
    const float* __restrict__ Wm0, const float* __restrict__ Ws0, const float* __restrict__ b0,
    const float* __restrict__ Wm1, const float* __restrict__ Ws1, const float* __restrict__ b1,
    const float* __restrict__ Wm2, const float* __restrict__ Ws2, const float* __restrict__ b2,
    const float* __restrict__ wcomb, const float* __restrict__ bcomb,
    const float* __restrict__ wrec, const unsigned char* __restrict__ clrec,
    const int* __restrict__ indptr,
    float* __restrict__ out, float* __restrict__ entpart, float* __restrict__ modpart)
{
    __shared__ float4 hb4[4096];       // h tile (64 KB)
    __shared__ float4 ab4[4096];       // agg tile (64 KB) — pool epilogue reuses this
    float* abf = (float*)ab4;
    const int t = threadIdx.x;
    const int bid = blockIdx.x;
    const int d = bid >> 8;
    const int b = bid & (NB - 1);
    const int rp = t >> 3;         // row pair
    const int o = t & 7;           // chunk owner (chunks o, o+8)
    const int fr = t >> 2;         // FC row
    const int fkq = t & 3;         // FC k-quad
    const int lane = t & 63;
    const int wave = t >> 6;

    // stage x -> hb (pair-keyed swizzle)
    {
        const float4* xv = (const float4*)(x + (size_t)b * NN * HID);
        #pragma unroll
        for (int it = 0; it < 4; ++it) {
            const int idx = t + it * 1024;
            const int nrow = idx >> 4, c = idx & 15;
            const int ph = (c & 8) | ((c & 7) ^ ((nrow >> 1) & 7));
            hb4[nrow * 16 + ph] = xv[idx];
        }
    }
    float p[4] = {0.f, 0.f, 0.f, 0.f};
    __syncthreads();   // [B0]

    const float* wp = wrec + (size_t)d * NB * EPG + (size_t)b * EPG;
    const unsigned char* clp = clrec + (size_t)b * EPG;
    const int* ipb = indptr + b * 257;
    const int js0 = ipb[rp * 2];
    const int je0 = ipb[rp * 2 + 1];
    const int je1 = ipb[rp * 2 + 2];

    layer_step<64, false>(rp, o, fr, fkq, js0, je0, je1, wp, clp, Wm0 + d*HID*HID,
                          Ws0 + d*HID*HID, b0 + d*HID, wcomb,          hb4, ab4, p);
    layer_step<64, false>(rp, o, fr, fkq, js0, je0, je1, wp, clp, Wm1 + d*HID*HID,
                          Ws1 + d*HID*HID, b1 + d*HID, wcomb + 64*16,  hb4, ab4, p);
    layer_step<16, true >(rp, o, fr, fkq, js0, je0, je1, wp, clp, Wm2 + d*HID*KK,
                          Ws2 + d*HID*KK,  b2 + d*KK,  wcomb + 128*16, hb4, ab4, p);

    // logits -> ab SL region (ab dead since L2's B2; own cells, no barrier needed)
    {
        float* dst = abf + SL_OFF + fr * 20 + fkq * 4;
        dst[0] = p[0]; dst[1] = p[1]; dst[2] = p[2]; dst[3] = p[3];
    }
    __syncthreads();   // [B6] logits visible

    // softmax + entropy (t<256); s overwrites logits region; s also -> out
    float ent_local = 0.f;
    if (t < 256) {
        const int rr = t;
        float* Lr = abf + SL_OFF + rr * 20;
        float logits[KK];
        #pragma unroll
        for (int k = 0; k < KK; ++k) logits[k] = Lr[k] + bcomb[k];
        float m = logits[0];
        #pragma unroll
        for (int k = 1; k < KK; ++k) m = fmaxf(m, logits[k]);
        float sum = 0.f, sv[KK];
        #pragma unroll
        for (int k = 0; k < KK; ++k) { sv[k] = expf(logits[k] - m); sum += sv[k]; }
        const float inv = 1.f / sum;
        float4* sp4 = (float4*)(out + S_OFF + ((size_t)(d * NB + b) * NN + rr) * KK);
        #pragma unroll
        for (int q4 = 0; q4 < 4; ++q4) {
            float4 v;
            const float s0 = sv[q4*4+0] * inv, s1 = sv[q4*4+1] * inv;
            const float s2 = sv[q4*4+2] * inv, s3 = sv[q4*4+3] * inv;
            v.x = s0; v.y = s1; v.z = s2; v.w = s3;
            sp4[q4] = v;
            *(float4*)(Lr + q4 * 4) = v;          // s into LDS
            ent_local -= s0 * logf(s0 + 1e-15f) + s1 * logf(s1 + 1e-15f)
                       + s2 * logf(s2 + 1e-15f) + s3 * logf(s3 + 1e-15f);
        }
    }
    #pragma unroll
    for (int off = 32; off; off >>= 1) ent_local += __shfl_down(ent_local, off);
    if (lane == 0) abf[ERED_OFF + wave] = ent_local;
    __syncthreads();   // [B7] s + ent partials visible
    if (t == 0) {
        float s = 0.f;
        #pragma unroll
        for (int w = 0; w < 16; ++w) s += abf[ERED_OFF + w];
        entpart[bid] = s;
    }

    // ---- fused pool (all in ab) ----
    // Phase A: G = A*s (thread=(row pr, kquad pkq)) + modularity partial, unrolled x2
    {
        const int pr = t >> 2, pkq = t & 3;
        const int pjs = ipb[pr], pje = ipb[pr + 1];
        const float4 sq = *(const float4*)(abf + SL_OFF + pr * 20 + pkq * 4);
        float g0 = 0.f, g1 = 0.f, g2 = 0.f, g3 = 0.f;
        float modp = 0.f;
        int j = pjs;
        #pragma unroll 1
        for (; j + 2 <= pje; j += 2) {
            const int cl0 = clp[j], cl1 = clp[j + 1];
            const float w0 = wp[j], w1 = wp[j + 1];
            const float4 sa = *(const float4*)(abf + SL_OFF + cl0 * 20 + pkq * 4);
            const float4 sb = *(const float4*)(abf + SL_OFF + cl1 * 20 + pkq * 4);
            g0 += w0 * sa.x + w1 * sb.x; g1 += w0 * sa.y + w1 * sb.y;
            g2 += w0 * sa.z + w1 * sb.z; g3 += w0 * sa.w + w1 * sb.w;
            const float a0 = sq.x - sa.x, a1 = sq.y - sa.y, a2 = sq.z - sa.z, a3 = sq.w - sa.w;
            const float b0v = sq.x - sb.x, b1v = sq.y - sb.y, b2v = sq.z - sb.z, b3v = sq.w - sb.w;
            modp += w0 * (a0*a0 + a1*a1 + a2*a2 + a3*a3)
                  + w1 * (b0v*b0v + b1v*b1v + b2v*b2v + b3v*b3v);
        }
        if (j < pje) {
            const int cl = clp[j];
            const float w = wp[j];
            const float4 sc4 = *(const float4*)(abf + SL_OFF + cl * 20 + pkq * 4);
            g0 += w * sc4.x; g1 += w * sc4.y; g2 += w * sc4.z; g3 += w * sc4.w;
            const float d0 = sq.x - sc4.x, d1 = sq.y - sc4.y;
            const float d2 = sq.z - sc4.z, d3 = sq.w - sc4.w;
            modp += w * (d0*d0 + d1*d1 + d2*d2 + d3*d3);
        }
        float4 gv; gv.x = g0; gv.y = g1; gv.z = g2; gv.w = g3;
        *(float4*)(abf + GL_OFF + pr * 20 + pkq * 4) = gv;
        #pragma unroll
        for (int off = 32; off; off >>= 1) modp += __shfl_down(modp, off);
        if (lane == 0) abf[MRED_OFF + wave] = modp;
    }
    __syncthreads();   // [B8] G + mod partials visible
    if (t == 0) {
        float s = 0.f;
        #pragma unroll
        for (int w = 0; w < 16; ++w) s += abf[MRED_OFF + w];
        modpart[bid] = s;
    }

    // Phase B: padj partials — thread (q=t>>8, k=(t>>4)&15, l=t&15) over rows [q*64,q*64+64)
    {
        const int q = t >> 8, kl = t & 255;
        const int k = kl >> 4, l = kl & 15;
        float acc = 0.f;
        const int r0 = q * 64;
        #pragma unroll 4
        for (int r = r0; r < r0 + 64; ++r)
            acc += abf[SL_OFF + r * 20 + k] * abf[GL_OFF + r * 20 + l];
        abf[PJW_OFF + q * 256 + kl] = acc;
    }

    // Phase C: px partials — thread (rg=t>>8, kg=(t>>6)&3, f=t&63) over rows [rg*64,+64)
    {
        const int rg = t >> 8, kg = (t >> 6) & 3, f = t & 63;
        const float* xp = x_to_pool + (size_t)b * NN * (64 * DIMS) + f * DIMS + d;
        float xa0 = 0.f, xa1 = 0.f, xa2 = 0.f, xa3 = 0.f;
        const int n0 = rg * 64;
        #pragma unroll 4
        for (int n = n0; n < n0 + 64; ++n) {
            const float xv = xp[(size_t)n * (64 * DIMS)];
            const float4 s4 = *(const float4*)(abf + SL_OFF + n * 20 + kg * 4);
            xa0 += xv * s4.x; xa1 += xv * s4.y; xa2 += xv * s4.z; xa3 += xv * s4.w;
        }
        float4 v; v.x = xa0; v.y = xa1; v.z = xa2; v.w = xa3;
        *(float4*)(abf + PXP_OFF + ((rg * 4 + kg) * 64 + f) * 4) = v;
    }
    __syncthreads();   // [B9] padj + px partials visible

    // Phase D merges (deterministic fixed-order sums)
    if (t < 256) {     // pea: (k,l) = (t>>4, t&15)
        const float v = (abf[PJW_OFF + t] + abf[PJW_OFF + 256 + t]
                       + abf[PJW_OFF + 512 + t] + abf[PJW_OFF + 768 + t]) * (1.f / 256.f);
        out[PEA_OFF + (size_t)((b * KK + (t >> 4)) * KK + (t & 15)) * DIMS + d] = v;
    }
    {                  // px: (k,f) = (t>>6, t&63)
        const int k = t >> 6, f = t & 63;
        const int kg = k >> 2, e = k & 3;
        float s = 0.f;
        #pragma unroll
        for (int rg = 0; rg < 4; ++rg)
            s += abf[PXP_OFF + ((rg * 4 + kg) * 64 + f) * 4 + e];
        out[PX_OFF + ((size_t)((b * KK + k) * 64) + f) * DIMS + d] = s * (1.f / 16.f);
    }
}

__global__ void aux_kernel(float* __restrict__ out)
{
    const int idx = blockIdx.x * 256 + threadIdx.x;
    if (idx < 2 * NTOT) {
        const int r = idx & (NTOT - 1);
        const int bb = r >> 8;
        const int j = r & 255;
        const int v = (idx < NTOT) ? (bb * KK + (j >> 4)) : (bb * KK + (j & 15));
        out[PEI_OFF + idx] = (float)v;
    } else if (idx < 2 * NTOT + NB * KK) {
        const int i = idx - 2 * NTOT;
        out[PB_OFF + i] = (float)(i >> 4);
    }
}

__global__ void loss_kernel(const float* __restrict__ entpart,
                            const float* __restrict__ modpart,
                            float* __restrict__ out)
{
    const int tid = threadIdx.x;
    float e = 0.f, m = 0.f;
    for (int i = tid; i < DIMS * NB; i += 256) { e += entpart[i]; m += modpart[i]; }
    #pragma unroll
    for (int off = 32; off; off >>= 1) { e += __shfl_down(e, off); m += __shfl_down(m, off); }
    __shared__ float er[4], mr[4];
    const int wave = tid >> 6, lane = tid & 63;
    if (lane == 0) { er[wave] = e; mr[wave] = m; }
    __syncthreads();
    if (tid == 0) {
        const float es = er[0] + er[1] + er[2] + er[3];
        const float ms = mr[0] + mr[1] + mr[2] + mr[3];
        out[LOSS_OFF] = ms / (float)NE + es / (float)(DIMS * NTOT);
    }
}

extern "C" void kernel_launch(void* const* d_in, const int* in_sizes, int n_in,
                              void* d_out, int out_size, void* d_ws, size_t ws_size,
                              hipStream_t stream)
{
    const float* x         = (const float*)d_in[0];
    const float* edge_attr = (const float*)d_in[1];
    const float* x_to_pool = (const float*)d_in[2];
    const float* Wm0 = (const float*)d_in[3];
    const float* Ws0 = (const float*)d_in[4];
    const float* b0  = (const float*)d_in[5];
    const float* Wm1 = (const float*)d_in[6];
    const float* Ws1 = (const float*)d_in[7];
    const float* b1  = (const float*)d_in[8];
    const float* Wm2 = (const float*)d_in[9];
    const float* Ws2 = (const float*)d_in[10];
    const float* b2  = (const float*)d_in[11];
    const float* fcW1= (const float*)d_in[12];
    const float* fcb1= (const float*)d_in[13];
    const float* fcW2= (const float*)d_in[14];
    const float* fcb2= (const float*)d_in[15];
    const int* edge_index = (const int*)d_in[16];
    float* out = (float*)d_out;
    char* ws = (char*)d_ws;
    float*         wrec  = (float*)(ws + WREC_WS);
    unsigned char* clrec = (unsigned char*)(ws + CLREC_WS);
    int*           iptr  = (int*)(ws + IPTR_WS);
    float*         entpart = (float*)(ws + ENT_WS);
    float*         modpart = (float*)(ws + MOD_WS);
    float*         wc    = (float*)(ws + WC_WS);
    float*         bc    = (float*)(ws + BC_WS);

    csr_build<<<dim3(NB), dim3(256), 0, stream>>>(edge_index, edge_attr, wrec, clrec, iptr);
    fc_combine<<<dim3(1), dim3(256), 0, stream>>>(fcW1, fcb1, fcW2, fcb2, wc, bc);
    gconv_kernel<<<dim3(DIMS * NB), dim3(1024), 0, stream>>>(
        x, x_to_pool, Wm0, Ws0, b0, Wm1, Ws1, b1, Wm2, Ws2, b2,
        wc, bc, wrec, clrec, iptr, out, entpart, modpart);
    aux_kernel<<<dim3((2 * NTOT + NB * KK + 255) / 256), dim3(256), 0, stream>>>(out);
    loss_kernel<<<dim3(1), dim3(256), 0, stream>>>(entpart, modpart, out);
}

// Round 22
// 550.967 us; speedup vs baseline: 1.0263x; 1.0186x over previous
//
#include <hip/hip_runtime.h>

#define DIMS 3
#define NB 256
#define NN 256
#define KK 16
#define HID 64
#define EPG 8192
#define NTOT (NB*NN)
#define NE (NB*EPG)

// d_out layout (flat concat of reference outputs, all as float)
#define PX_OFF   0          // (B*K, F, DIMS)           = 786432
#define PEI_OFF  786432     // (2, B*K*K)               = 131072
#define PEA_OFF  917504     // (B*K*K, DIMS)            = 196608
#define PB_OFF   1114112    // (B*K,)                   = 4096
#define LOSS_OFF 1118208    // scalar
#define S_OFF    1118209    // (DIMS, B, N, K)          = 3145728

// d_ws layout (bytes) — total ~27.5 MB
#define WREC_WS  0                 // float[3][NB*EPG] per-d edge weight (CSR order) = 24 MB
#define CLREC_WS 25165824          // uchar[NB*EPG] col-local index
#define IPTR_WS  27262976          // int[NB*257]
#define ENT_WS   27526144          // float[768]
#define MOD_WS   27529216          // float[768]
#define WC_WS    27532288          // float[144*16]  (fcW1 @ fcW2)
#define BC_WS    27541504          // float[16]      (fcb1 @ fcW2 + fcb2)

// Pool-epilogue regions live in the (dead) agg buffer ab (16384 floats):
#define SL_OFF   0         // s tile      [256][20]  -> [0, 5120)
#define GL_OFF   5120      // G tile      [256][20]  -> [5120, 10240)
#define PXP_OFF  10240     // px partials [16][64][4]-> [10240, 14336)
#define PJW_OFF  14336     // padj part.  [4][256]   -> [14336, 15360)
#define MRED_OFF 15360     // mod red     [16]
#define ERED_OFF 15380     // ent red     [16]

// h/agg layout map: logical (row, chunk c in 0..15) stored at
//   phys(c,row) = (c&8) | ((c&7) ^ ((row>>1)&7))  (pair-keyed swizzle)

// ------- CSR build v2: contiguous 64-edge chunks (int4/float4 vectorized loads),
// fc_combine folded into block 0, aux constant-writes spread across all blocks. -------
#define HSTR 132
#define PSTR 129
__launch_bounds__(256)
__global__ void csr_build(const int* __restrict__ edge_index,
                          const float* __restrict__ edge_attr,
                          const float* __restrict__ fcW1, const float* __restrict__ fcb1,
                          const float* __restrict__ fcW2, const float* __restrict__ fcb2,
                          float* __restrict__ wrec, unsigned char* __restrict__ clrec,
                          int* __restrict__ indptr,
                          float* __restrict__ wc, float* __restrict__ bc,
                          float* __restrict__ out)
{
    __shared__ unsigned char  h[256 * HSTR];    // 33.8 KB
    __shared__ unsigned short po[256 * PSTR];   // 66.0 KB
    __shared__ int sc[256];
    const int b = blockIdx.x;
    const int t = threadIdx.x;
    const int* rowp = edge_index + (size_t)b * EPG;
    const int* colp = edge_index + (size_t)NB * EPG + (size_t)b * EPG;

    for (int i = t; i < 256 * HSTR / 4; i += 256) ((unsigned int*)h)[i] = 0u;

    // aux constants: 528 elements per block (135168 = 528*256 total)
    {
        const int base = b * 528;
        #pragma unroll
        for (int u = 0; u < 3; ++u) {
            const int idx = base + t + u * 256;
            if (idx < base + 528) {
                if (idx < 2 * NTOT) {
                    const int r = idx & (NTOT - 1);
                    const int bb = r >> 8;
                    const int j = r & 255;
                    const int v = (idx < NTOT) ? (bb * KK + (j >> 4)) : (bb * KK + (j & 15));
                    out[PEI_OFF + idx] = (float)v;
                } else {
                    const int i = idx - 2 * NTOT;
                    out[PB_OFF + i] = (float)(i >> 4);
                }
            }
        }
    }
    // fc_combine on block 0 (independent of CSR work)
    if (b == 0) {
        for (int idx = t; idx < 144 * 16; idx += 256) {
            const int i = idx >> 4, k = idx & 15;
            float s = 0.f;
            for (int q = 0; q < 50; ++q) s += fcW1[i * 50 + q] * fcW2[q * 16 + k];
            wc[idx] = s;
        }
        if (t < 16) {
            float s = fcb2[t];
            for (int q = 0; q < 50; ++q) s += fcb1[q] * fcW2[q * 16 + t];
            bc[t] = s;
        }
    }
    __syncthreads();

    // phase A: histogram; thread t<128 owns CONTIGUOUS edges [64t, 64t+64)
    if (t < 128) {
        const int4* rp4 = (const int4*)(rowp + 64 * t);
        #pragma unroll 4
        for (int j = 0; j < 16; ++j) {
            const int4 r4 = rp4[j];
            h[(r4.x & (NN - 1)) * HSTR + t]++;
            h[(r4.y & (NN - 1)) * HSTR + t]++;
            h[(r4.z & (NN - 1)) * HSTR + t]++;
            h[(r4.w & (NN - 1)) * HSTR + t]++;
        }
    }
    __syncthreads();

    // B1: row totals (row = t); pad bytes are zero
    int tot;
    {
        int s = 0;
        const unsigned int* hr = (const unsigned int*)(h + t * HSTR);
        #pragma unroll
        for (int c4 = 0; c4 < HSTR / 4; ++c4) {
            const unsigned int v = hr[c4];
            s += (v & 255) + ((v >> 8) & 255) + ((v >> 16) & 255) + (v >> 24);
        }
        tot = s;
        sc[t] = s;
    }
    __syncthreads();
    for (int ofs = 1; ofs < 256; ofs <<= 1) {
        int v = (t >= ofs) ? sc[t - ofs] : 0;
        __syncthreads();
        sc[t] += v;
        __syncthreads();
    }
    const int start = sc[t] - tot;
    indptr[b * 257 + t] = start;
    if (t == 255) indptr[b * 257 + 256] = EPG;

    // B2: running prefix po[t][c] over chunks
    {
        int run = start;
        #pragma unroll 4
        for (int c = 0; c < 128; ++c) {
            po[t * PSTR + c] = (unsigned short)run;
            run += h[t * HSTR + c];
        }
    }
    __syncthreads();

    // phase C: place edges; thread t<128, contiguous [64t, 64t+64), 4 at a time
    if (t < 128) {
        const int4*  rp4 = (const int4*)(rowp + 64 * t);
        const int4*  cp4 = (const int4*)(colp + 64 * t);
        const float4* ep4 = (const float4*)(edge_attr + (size_t)b * EPG * 3 + (size_t)192 * t);
        float* w0 = wrec + (size_t)b * EPG;
        float* w1 = wrec + (size_t)NB * EPG + (size_t)b * EPG;
        float* w2 = wrec + 2 * (size_t)NB * EPG + (size_t)b * EPG;
        unsigned char* cdst = clrec + (size_t)b * EPG;
        #pragma unroll 2
        for (int j = 0; j < 16; ++j) {
            const int4 r4 = rp4[j];
            const int4 c4 = cp4[j];
            const float4 fa = ep4[j * 3 + 0];
            const float4 fb = ep4[j * 3 + 1];
            const float4 fcv = ep4[j * 3 + 2];
            const float f[12] = {fa.x, fa.y, fa.z, fa.w, fb.x, fb.y, fb.z, fb.w,
                                 fcv.x, fcv.y, fcv.z, fcv.w};
            const int rv[4] = {r4.x & (NN - 1), r4.y & (NN - 1), r4.z & (NN - 1), r4.w & (NN - 1)};
            const int cv[4] = {c4.x & (NN - 1), c4.y & (NN - 1), c4.z & (NN - 1), c4.w & (NN - 1)};
            #pragma unroll
            for (int u = 0; u < 4; ++u) {
                const int dest = po[rv[u] * PSTR + t]++;
                w0[dest] = f[u * 3 + 0];
                w1[dest] = f[u * 3 + 1];
                w2[dest] = f[u * 3 + 2];
                cdst[dest] = (unsigned char)cv[u];
            }
        }
    }
}

// -------- gconv v21 (unchanged from R21): two LDS buffers, 2 barriers/layer,
// fused dual-row gather (x2 unroll), pair-keyed swizzle, fused pool epilogue. --------
template<int OUTW, bool IS_L2>
__device__ __forceinline__ void layer_step(
    int rp, int o, int fr, int fkq, int js0, int je0, int je1,
    const float* __restrict__ wp, const unsigned char* __restrict__ clp,
    const float* __restrict__ Wm, const float* __restrict__ Ws,
    const float* __restrict__ bias, const float* __restrict__ wc, // wcomb + layer_row_off*16
    float4* hb4, float4* ab4, float* p)
{
    constexpr int NCO = OUTW / 8;              // outputs/thread/row: 8 (L0/L1), 2 (L2)
    const int swz = rp & 7;                    // shared swizzle key for this row pair
    const int base = rp * 32;                  // row0 chunk base (row1 = +16)

    // P1: fused dual-row gather, unrolled x2 (reads hb)
    float ga0[8], ga1[8];
    #pragma unroll
    for (int u = 0; u < 8; ++u) { ga0[u] = 0.f; ga1[u] = 0.f; }
    {
        const int n0 = je0 - js0, n1 = je1 - je0;
        const int nmin = (n0 < n1) ? n0 : n1;
        int i = 0;
        #pragma unroll 1
        for (; i + 2 <= nmin; i += 2) {
            const int cla0 = clp[js0 + i],     clb0 = clp[je0 + i];
            const int cla1 = clp[js0 + i + 1], clb1 = clp[je0 + i + 1];
            const float wa0 = wp[js0 + i],     wb0 = wp[je0 + i];
            const float wa1 = wp[js0 + i + 1], wb1 = wp[je0 + i + 1];
            const int ia0 = cla0 * 16 + (o ^ ((cla0 >> 1) & 7));
            const int ib0 = clb0 * 16 + (o ^ ((clb0 >> 1) & 7));
            const int ia1 = cla1 * 16 + (o ^ ((cla1 >> 1) & 7));
            const int ib1 = clb1 * 16 + (o ^ ((clb1 >> 1) & 7));
            const float4 xa00 = hb4[ia0];
            const float4 xa01 = hb4[ia0 + 8];
            const float4 xb00 = hb4[ib0];
            const float4 xb01 = hb4[ib0 + 8];
            const float4 xa10 = hb4[ia1];
            const float4 xa11 = hb4[ia1 + 8];
            const float4 xb10 = hb4[ib1];
            const float4 xb11 = hb4[ib1 + 8];
            ga0[0] += wa0 * xa00.x + wa1 * xa10.x;
            ga0[1] += wa0 * xa00.y + wa1 * xa10.y;
            ga0[2] += wa0 * xa00.z + wa1 * xa10.z;
            ga0[3] += wa0 * xa00.w + wa1 * xa10.w;
            ga0[4] += wa0 * xa01.x + wa1 * xa11.x;
            ga0[5] += wa0 * xa01.y + wa1 * xa11.y;
            ga0[6] += wa0 * xa01.z + wa1 * xa11.z;
            ga0[7] += wa0 * xa01.w + wa1 * xa11.w;
            ga1[0] += wb0 * xb00.x + wb1 * xb10.x;
            ga1[1] += wb0 * xb00.y + wb1 * xb10.y;
            ga1[2] += wb0 * xb00.z + wb1 * xb10.z;
            ga1[3] += wb0 * xb00.w + wb1 * xb10.w;
            ga1[4] += wb0 * xb01.x + wb1 * xb11.x;
            ga1[5] += wb0 * xb01.y + wb1 * xb11.y;
            ga1[6] += wb0 * xb01.z + wb1 * xb11.z;
            ga1[7] += wb0 * xb01.w + wb1 * xb11.w;
        }
        #pragma unroll 1
        for (; i < nmin; ++i) {
            const int cla = clp[js0 + i];
            const int clb = clp[je0 + i];
            const float wa = wp[js0 + i];
            const float wb = wp[je0 + i];
            const int ia = cla * 16 + (o ^ ((cla >> 1) & 7));
            const int ib = clb * 16 + (o ^ ((clb >> 1) & 7));
            const float4 a0 = hb4[ia];
            const float4 a1 = hb4[ia + 8];
            const float4 bb0 = hb4[ib];
            const float4 bb1 = hb4[ib + 8];
            ga0[0] += wa * a0.x; ga0[1] += wa * a0.y; ga0[2] += wa * a0.z; ga0[3] += wa * a0.w;
            ga0[4] += wa * a1.x; ga0[5] += wa * a1.y; ga0[6] += wa * a1.z; ga0[7] += wa * a1.w;
            ga1[0] += wb * bb0.x; ga1[1] += wb * bb0.y; ga1[2] += wb * bb0.z; ga1[3] += wb * bb0.w;
            ga1[4] += wb * bb1.x; ga1[5] += wb * bb1.y; ga1[6] += wb * bb1.z; ga1[7] += wb * bb1.w;
        }
        #pragma unroll 1
        for (int j = js0 + nmin; j < je0; ++j) {
            const int cl = clp[j];
            const float w = wp[j];
            const int ia = cl * 16 + (o ^ ((cl >> 1) & 7));
            const float4 ha = hb4[ia];
            const float4 hb = hb4[ia + 8];
            ga0[0] += w * ha.x; ga0[1] += w * ha.y; ga0[2] += w * ha.z; ga0[3] += w * ha.w;
            ga0[4] += w * hb.x; ga0[5] += w * hb.y; ga0[6] += w * hb.z; ga0[7] += w * hb.w;
        }
        #pragma unroll 1
        for (int j = je0 + nmin; j < je1; ++j) {
            const int cl = clp[j];
            const float w = wp[j];
            const int ia = cl * 16 + (o ^ ((cl >> 1) & 7));
            const float4 ha = hb4[ia];
            const float4 hb = hb4[ia + 8];
            ga1[0] += w * ha.x; ga1[1] += w * ha.y; ga1[2] += w * ha.z; ga1[3] += w * ha.w;
            ga1[4] += w * hb.x; ga1[5] += w * hb.y; ga1[6] += w * hb.z; ga1[7] += w * hb.w;
        }
    }
    // write agg -> ab (own cells; overlaps P2; fenced by B1 before P4 reads)
    {
        const int i0 = base + (o ^ swz);
        float4 v;
        v.x = ga0[0]; v.y = ga0[1]; v.z = ga0[2]; v.w = ga0[3]; ab4[i0] = v;
        v.x = ga0[4]; v.y = ga0[5]; v.z = ga0[6]; v.w = ga0[7]; ab4[i0 + 8] = v;
        v.x = ga1[0]; v.y = ga1[1]; v.z = ga1[2]; v.w = ga1[3]; ab4[i0 + 16] = v;
        v.x = ga1[4]; v.y = ga1[5]; v.z = ga1[6]; v.w = ga1[7]; ab4[i0 + 24] = v;
    }

    // P2: acc = bias + h@Ws (reads hb)
    const int jA = o * 4;
    const int jB = o * 4 + 32;
    const int j0L2 = o * NCO;
    float acc0[NCO == 8 ? 8 : 2], acc1[NCO == 8 ? 8 : 2];
    if constexpr (NCO == 8) {
        const float4 bv0 = *(const float4*)(bias + jA);
        const float4 bv1 = *(const float4*)(bias + jB);
        acc0[0]=bv0.x; acc0[1]=bv0.y; acc0[2]=bv0.z; acc0[3]=bv0.w;
        acc0[4]=bv1.x; acc0[5]=bv1.y; acc0[6]=bv1.z; acc0[7]=bv1.w;
        #pragma unroll
        for (int u = 0; u < 8; ++u) acc1[u] = acc0[u];
    } else {
        acc0[0] = bias[j0L2]; acc0[1] = bias[j0L2 + 1];
        acc1[0] = acc0[0];    acc1[1] = acc0[1];
    }
    #pragma unroll 1
    for (int ic = 0; ic < 16; ++ic) {
        const int ip = base + ((ic & 8) | ((ic & 7) ^ swz));
        const float4 h40 = hb4[ip];
        const float4 h41 = hb4[ip + 16];
        const float hv0[4] = {h40.x, h40.y, h40.z, h40.w};
        const float hv1[4] = {h41.x, h41.y, h41.z, h41.w};
        #pragma unroll
        for (int u = 0; u < 4; ++u) {
            const float* wr = Ws + (ic * 4 + u) * OUTW;
            const float a0 = hv0[u], a1 = hv1[u];
            if constexpr (NCO == 8) {
                const float4 wa = *(const float4*)(wr + jA);
                const float4 wb = *(const float4*)(wr + jB);
                acc0[0]+=a0*wa.x; acc0[1]+=a0*wa.y; acc0[2]+=a0*wa.z; acc0[3]+=a0*wa.w;
                acc0[4]+=a0*wb.x; acc0[5]+=a0*wb.y; acc0[6]+=a0*wb.z; acc0[7]+=a0*wb.w;
                acc1[0]+=a1*wa.x; acc1[1]+=a1*wa.y; acc1[2]+=a1*wa.z; acc1[3]+=a1*wa.w;
                acc1[4]+=a1*wb.x; acc1[5]+=a1*wb.y; acc1[6]+=a1*wb.z; acc1[7]+=a1*wb.w;
            } else {
                const float2 w2 = *(const float2*)(wr + j0L2);
                acc0[0]+=a0*w2.x; acc0[1]+=a0*w2.y;
                acc1[0]+=a1*w2.x; acc1[1]+=a1*w2.y;
            }
        }
    }
    __syncthreads();   // [B1] ab writes visible; all hb reads of this layer done

    // P4: acc += ab@Wm
    #pragma unroll 1
    for (int ic = 0; ic < 16; ++ic) {
        const int ip = base + ((ic & 8) | ((ic & 7) ^ swz));
        const float4 a40 = ab4[ip];
        const float4 a41 = ab4[ip + 16];
        const float av0[4] = {a40.x, a40.y, a40.z, a40.w};
        const float av1[4] = {a41.x, a41.y, a41.z, a41.w};
        #pragma unroll
        for (int u = 0; u < 4; ++u) {
            const float* wr = Wm + (ic * 4 + u) * OUTW;
            const float a0 = av0[u], a1 = av1[u];
            if constexpr (NCO == 8) {
                const float4 wa = *(const float4*)(wr + jA);
                const float4 wb = *(const float4*)(wr + jB);
                acc0[0]+=a0*wa.x; acc0[1]+=a0*wa.y; acc0[2]+=a0*wa.z; acc0[3]+=a0*wa.w;
                acc0[4]+=a0*wb.x; acc0[5]+=a0*wb.y; acc0[6]+=a0*wb.z; acc0[7]+=a0*wb.w;
                acc1[0]+=a1*wa.x; acc1[1]+=a1*wa.y; acc1[2]+=a1*wa.z; acc1[3]+=a1*wa.w;
                acc1[4]+=a1*wb.x; acc1[5]+=a1*wb.y; acc1[6]+=a1*wb.z; acc1[7]+=a1*wb.w;
            } else {
                const float2 w2 = *(const float2*)(wr + j0L2);
                acc0[0]+=a0*w2.x; acc0[1]+=a0*w2.y;
                acc1[0]+=a1*w2.x; acc1[1]+=a1*w2.y;
            }
        }
    }
    #pragma unroll
    for (int jj = 0; jj < NCO; ++jj) {
        acc0[jj] = fmaxf(acc0[jj], 0.f);
        acc1[jj] = fmaxf(acc1[jj], 0.f);
    }

    // P5: write h_next -> hb (own cells; prior hb reads fenced by B1)
    if constexpr (!IS_L2) {
        const int i0 = base + (o ^ swz);
        float4 v;
        v.x = acc0[0]; v.y = acc0[1]; v.z = acc0[2]; v.w = acc0[3]; hb4[i0] = v;
        v.x = acc0[4]; v.y = acc0[5]; v.z = acc0[6]; v.w = acc0[7]; hb4[i0 + 8] = v;
        v.x = acc1[0]; v.y = acc1[1]; v.z = acc1[2]; v.w = acc1[3]; hb4[i0 + 16] = v;
        v.x = acc1[4]; v.y = acc1[5]; v.z = acc1[6]; v.w = acc1[7]; hb4[i0 + 24] = v;
    } else {
        float* hbf = (float*)hb4;
        const int cc = o >> 1, off = (o & 1) * 2;
        const int ph = cc ^ swz;
        float* p0 = hbf + (base + ph) * 4 + off;
        float* p1 = hbf + (base + 16 + ph) * 4 + off;
        p0[0] = acc0[0]; p0[1] = acc0[1];
        p1[0] = acc1[0]; p1[1] = acc1[1];
    }
    __syncthreads();   // [B2] h_next visible; ab reads done

    // FC: thread (fr,fkq) accumulates p[4] += h_next[fr][:] @ Wc[:, fkq*4..+4]
    {
        const int rb = fr * 16, rs = (fr >> 1) & 7;
        if constexpr (!IS_L2) {
            #pragma unroll 2
            for (int c4 = 0; c4 < 16; ++c4) {
                const float4 v4 = hb4[rb + ((c4 & 8) | ((c4 & 7) ^ rs))];
                const float vv[4] = {v4.x, v4.y, v4.z, v4.w};
                #pragma unroll
                for (int e = 0; e < 4; ++e) {
                    const float4 w4 = *(const float4*)(wc + (c4 * 4 + e) * 16 + fkq * 4);
                    p[0] += vv[e] * w4.x; p[1] += vv[e] * w4.y;
                    p[2] += vv[e] * w4.z; p[3] += vv[e] * w4.w;
                }
            }
        } else {
            #pragma unroll 2
            for (int c4 = 0; c4 < 4; ++c4) {
                const float4 v4 = hb4[rb + (c4 ^ rs)];
                const float vv[4] = {v4.x, v4.y, v4.z, v4.w};
                #pragma unroll
                for (int e = 0; e < 4; ++e) {
                    const float4 w4 = *(const float4*)(wc + (c4 * 4 + e) * 16 + fkq * 4);
                    p[0] += vv[e] * w4.x; p[1] += vv[e] * w4.y;
                    p[2] += vv[e] * w4.z; p[3] += vv[e] * w4.w;
                }
            }
        }
    }
    // no trailing barrier: next layer reads hb (safe concurrent) and writes ab
    // (this layer's ab reads fenced by B2).
}

__launch_bounds__(1024)
__global__ void gconv_kernel(
    const float* __restrict__ x,
    const float* __restrict__ x_to_pool,
    const float* __restrict__ Wm0, const float* __restrict__ Ws0, const float* __restrict__ b0,
    const float* __restrict__ Wm1, const float* __restrict__ Ws1, const float* __restrict__ b1,
    const float* __restrict__ Wm2, const float* __restrict__ Ws2, const float* __restrict__ b2,
    const float* __restrict__ wcomb, const float* __restrict__ bcomb,
    const float* __restrict__ wrec, const unsigned char* __restrict__ clrec,
    const int* __restrict__ indptr,
    float* __restrict__ out, float* __restrict__ entpart, float* __restrict__ modpart)
{
    __shared__ float4 hb4[4096];       // h tile (64 KB)
    __shared__ float4 ab4[4096];       // agg tile (64 KB) — pool epilogue reuses this
    float* abf = (float*)ab4;
    const int t = threadIdx.x;
    const int bid = blockIdx.x;
    const int d = bid >> 8;
    const int b = bid & (NB - 1);
    const int rp = t >> 3;         // row pair
    const int o = t & 7;           // chunk owner (chunks o, o+8)
    const int fr = t >> 2;         // FC row
    const int fkq = t & 3;         // FC k-quad
    const int lane = t & 63;
    const int wave = t >> 6;

    // stage x -> hb (pair-keyed swizzle)
    {
        const float4* xv = (const float4*)(x + (size_t)b * NN * HID);
        #pragma unroll
        for (int it = 0; it < 4; ++it) {
            const int idx = t + it * 1024;
            const int nrow = idx >> 4, c = idx & 15;
            const int ph = (c & 8) | ((c & 7) ^ ((nrow >> 1) & 7));
            hb4[nrow * 16 + ph] = xv[idx];
        }
    }
    float p[4] = {0.f, 0.f, 0.f, 0.f};
    __syncthreads();   // [B0]

    const float* wp = wrec + (size_t)d * NB * EPG + (size_t)b * EPG;
    const unsigned char* clp = clrec + (size_t)b * EPG;
    const int* ipb = indptr + b * 257;
    const int js0 = ipb[rp * 2];
    const int je0 = ipb[rp * 2 + 1];
    const int je1 = ipb[rp * 2 + 2];

    layer_step<64, false>(rp, o, fr, fkq, js0, je0, je1, wp, clp, Wm0 + d*HID*HID,
                          Ws0 + d*HID*HID, b0 + d*HID, wcomb,          hb4, ab4, p);
    layer_step<64, false>(rp, o, fr, fkq, js0, je0, je1, wp, clp, Wm1 + d*HID*HID,
                          Ws1 + d*HID*HID, b1 + d*HID, wcomb + 64*16,  hb4, ab4, p);
    layer_step<16, true >(rp, o, fr, fkq, js0, je0, je1, wp, clp, Wm2 + d*HID*KK,
                          Ws2 + d*HID*KK,  b2 + d*KK,  wcomb + 128*16, hb4, ab4, p);

    // logits -> ab SL region (ab dead since L2's B2; own cells, no barrier needed)
    {
        float* dst = abf + SL_OFF + fr * 20 + fkq * 4;
        dst[0] = p[0]; dst[1] = p[1]; dst[2] = p[2]; dst[3] = p[3];
    }
    __syncthreads();   // [B6] logits visible

    // softmax + entropy (t<256); s overwrites logits region; s also -> out
    float ent_local = 0.f;
    if (t < 256) {
        const int rr = t;
        float* Lr = abf + SL_OFF + rr * 20;
        float logits[KK];
        #pragma unroll
        for (int k = 0; k < KK; ++k) logits[k] = Lr[k] + bcomb[k];
        float m = logits[0];
        #pragma unroll
        for (int k = 1; k < KK; ++k) m = fmaxf(m, logits[k]);
        float sum = 0.f, sv[KK];
        #pragma unroll
        for (int k = 0; k < KK; ++k) { sv[k] = expf(logits[k] - m); sum += sv[k]; }
        const float inv = 1.f / sum;
        float4* sp4 = (float4*)(out + S_OFF + ((size_t)(d * NB + b) * NN + rr) * KK);
        #pragma unroll
        for (int q4 = 0; q4 < 4; ++q4) {
            float4 v;
            const float s0 = sv[q4*4+0] * inv, s1 = sv[q4*4+1] * inv;
            const float s2 = sv[q4*4+2] * inv, s3 = sv[q4*4+3] * inv;
            v.x = s0; v.y = s1; v.z = s2; v.w = s3;
            sp4[q4] = v;
            *(float4*)(Lr + q4 * 4) = v;          // s into LDS
            ent_local -= s0 * logf(s0 + 1e-15f) + s1 * logf(s1 + 1e-15f)
                       + s2 * logf(s2 + 1e-15f) + s3 * logf(s3 + 1e-15f);
        }
    }
    #pragma unroll
    for (int off = 32; off; off >>= 1) ent_local += __shfl_down(ent_local, off);
    if (lane == 0) abf[ERED_OFF + wave] = ent_local;
    __syncthreads();   // [B7] s + ent partials visible
    if (t == 0) {
        float s = 0.f;
        #pragma unroll
        for (int w = 0; w < 16; ++w) s += abf[ERED_OFF + w];
        entpart[bid] = s;
    }

    // ---- fused pool (all in ab) ----
    // Phase A: G = A*s (thread=(row pr, kquad pkq)) + modularity partial, unrolled x2
    {
        const int pr = t >> 2, pkq = t & 3;
        const int pjs = ipb[pr], pje = ipb[pr + 1];
        const float4 sq = *(const float4*)(abf + SL_OFF + pr * 20 + pkq * 4);
        float g0 = 0.f, g1 = 0.f, g2 = 0.f, g3 = 0.f;
        float modp = 0.f;
        int j = pjs;
        #pragma unroll 1
        for (; j + 2 <= pje; j += 2) {
            const int cl0 = clp[j], cl1 = clp[j + 1];
            const float w0 = wp[j], w1 = wp[j + 1];
            const float4 sa = *(const float4*)(abf + SL_OFF + cl0 * 20 + pkq * 4);
            const float4 sb = *(const float4*)(abf + SL_OFF + cl1 * 20 + pkq * 4);
            g0 += w0 * sa.x + w1 * sb.x; g1 += w0 * sa.y + w1 * sb.y;
            g2 += w0 * sa.z + w1 * sb.z; g3 += w0 * sa.w + w1 * sb.w;
            const float a0 = sq.x - sa.x, a1 = sq.y - sa.y, a2 = sq.z - sa.z, a3 = sq.w - sa.w;
            const float b0v = sq.x - sb.x, b1v = sq.y - sb.y, b2v = sq.z - sb.z, b3v = sq.w - sb.w;
            modp += w0 * (a0*a0 + a1*a1 + a2*a2 + a3*a3)
                  + w1 * (b0v*b0v + b1v*b1v + b2v*b2v + b3v*b3v);
        }
        if (j < pje) {
            const int cl = clp[j];
            const float w = wp[j];
            const float4 sc4 = *(const float4*)(abf + SL_OFF + cl * 20 + pkq * 4);
            g0 += w * sc4.x; g1 += w * sc4.y; g2 += w * sc4.z; g3 += w * sc4.w;
            const float d0 = sq.x - sc4.x, d1 = sq.y - sc4.y;
            const float d2 = sq.z - sc4.z, d3 = sq.w - sc4.w;
            modp += w * (d0*d0 + d1*d1 + d2*d2 + d3*d3);
        }
        float4 gv; gv.x = g0; gv.y = g1; gv.z = g2; gv.w = g3;
        *(float4*)(abf + GL_OFF + pr * 20 + pkq * 4) = gv;
        #pragma unroll
        for (int off = 32; off; off >>= 1) modp += __shfl_down(modp, off);
        if (lane == 0) abf[MRED_OFF + wave] = modp;
    }
    __syncthreads();   // [B8] G + mod partials visible
    if (t == 0) {
        float s = 0.f;
        #pragma unroll
        for (int w = 0; w < 16; ++w) s += abf[MRED_OFF + w];
        modpart[bid] = s;
    }

    // Phase B: padj partials — thread (q=t>>8, k=(t>>4)&15, l=t&15) over rows [q*64,q*64+64)
    {
        const int q = t >> 8, kl = t & 255;
        const int k = kl >> 4, l = kl & 15;
        float acc = 0.f;
        const int r0 = q * 64;
        #pragma unroll 4
        for (int r = r0; r < r0 + 64; ++r)
            acc += abf[SL_OFF + r * 20 + k] * abf[GL_OFF + r * 20 + l];
        abf[PJW_OFF + q * 256 + kl] = acc;
    }

    // Phase C: px partials — thread (rg=t>>8, kg=(t>>6)&3, f=t&63) over rows [rg*64,+64)
    {
        const int rg = t >> 8, kg = (t >> 6) & 3, f = t & 63;
        const float* xp = x_to_pool + (size_t)b * NN * (64 * DIMS) + f * DIMS + d;
        float xa0 = 0.f, xa1 = 0.f, xa2 = 0.f, xa3 = 0.f;
        const int n0 = rg * 64;
        #pragma unroll 4
        for (int n = n0; n < n0 + 64; ++n) {
            const float xv = xp[(size_t)n * (64 * DIMS)];
            const float4 s4 = *(const float4*)(abf + SL_OFF + n * 20 + kg * 4);
            xa0 += xv * s4.x; xa1 += xv * s4.y; xa2 += xv * s4.z; xa3 += xv * s4.w;
        }
        float4 v; v.x = xa0; v.y = xa1; v.z = xa2; v.w = xa3;
        *(float4*)(abf + PXP_OFF + ((rg * 4 + kg) * 64 + f) * 4) = v;
    }
    __syncthreads();   // [B9] padj + px partials visible

    // Phase D merges (deterministic fixed-order sums)
    if (t < 256) {     // pea: (k,l) = (t>>4, t&15)
        const float v = (abf[PJW_OFF + t] + abf[PJW_OFF + 256 + t]
                       + abf[PJW_OFF + 512 + t] + abf[PJW_OFF + 768 + t]) * (1.f / 256.f);
        out[PEA_OFF + (size_t)((b * KK + (t >> 4)) * KK + (t & 15)) * DIMS + d] = v;
    }
    {                  // px: (k,f) = (t>>6, t&63)
        const int k = t >> 6, f = t & 63;
        const int kg = k >> 2, e = k & 3;
        float s = 0.f;
        #pragma unroll
        for (int rg = 0; rg < 4; ++rg)
            s += abf[PXP_OFF + ((rg * 4 + kg) * 64 + f) * 4 + e];
        out[PX_OFF + ((size_t)((b * KK + k) * 64) + f) * DIMS + d] = s * (1.f / 16.f);
    }
}

__global__ void loss_kernel(const float* __restrict__ entpart,
                            const float* __restrict__ modpart,
                            float* __restrict__ out)
{
    const int tid = threadIdx.x;
    float e = 0.f, m = 0.f;
    for (int i = tid; i < DIMS * NB; i += 256) { e += entpart[i]; m += modpart[i]; }
    #pragma unroll
    for (int off = 32; off; off >>= 1) { e += __shfl_down(e, off); m += __shfl_down(m, off); }
    __shared__ float er[4], mr[4];
    const int wave = tid >> 6, lane = tid & 63;
    if (lane == 0) { er[wave] = e; mr[wave] = m; }
    __syncthreads();
    if (tid == 0) {
        const float es = er[0] + er[1] + er[2] + er[3];
        const float ms = mr[0] + mr[1] + mr[2] + mr[3];
        out[LOSS_OFF] = ms / (float)NE + es / (float)(DIMS * NTOT);
    }
}

extern "C" void kernel_launch(void* const* d_in, const int* in_sizes, int n_in,
                              void* d_out, int out_size, void* d_ws, size_t ws_size,
                              hipStream_t stream)
{
    const float* x         = (const float*)d_in[0];
    const float* edge_attr = (const float*)d_in[1];
    const float* x_to_pool = (const float*)d_in[2];
    const float* Wm0 = (const float*)d_in[3];
    const float* Ws0 = (const float*)d_in[4];
    const float* b0  = (const float*)d_in[5];
    const float* Wm1 = (const float*)d_in[6];
    const float* Ws1 = (const float*)d_in[7];
    const float* b1  = (const float*)d_in[8];
    const float* Wm2 = (const float*)d_in[9];
    const float* Ws2 = (const float*)d_in[10];
    const float* b2  = (const float*)d_in[11];
    const float* fcW1= (const float*)d_in[12];
    const float* fcb1= (const float*)d_in[13];
    const float* fcW2= (const float*)d_in[14];
    const float* fcb2= (const float*)d_in[15];
    const int* edge_index = (const int*)d_in[16];
    float* out = (float*)d_out;
    char* ws = (char*)d_ws;
    float*         wrec  = (float*)(ws + WREC_WS);
    unsigned char* clrec = (unsigned char*)(ws + CLREC_WS);
    int*           iptr  = (int*)(ws + IPTR_WS);
    float*         entpart = (float*)(ws + ENT_WS);
    float*         modpart = (float*)(ws + MOD_WS);
    float*         wc    = (float*)(ws + WC_WS);
    float*         bc    = (float*)(ws + BC_WS);

    csr_build<<<dim3(NB), dim3(256), 0, stream>>>(
        edge_index, edge_attr, fcW1, fcb1, fcW2, fcb2,
        wrec, clrec, iptr, wc, bc, out);
    gconv_kernel<<<dim3(DIMS * NB), dim3(1024), 0, stream>>>(
        x, x_to_pool, Wm0, Ws0, b0, Wm1, Ws1, b1, Wm2, Ws2, b2,
        wc, bc, wrec, clrec, iptr, out, entpart, modpart);
    loss_kernel<<<dim3(1), dim3(256), 0, stream>>>(entpart, modpart, out);
}